// Round 7
// baseline (1517.748 us; speedup 1.0000x reference)
//
#include <hip/hip_runtime.h>
#include <hip/hip_bf16.h>
#include <math.h>

// MorphingGNN MI355X — round 6: gather restructured to scalar-base coalesced
// dword gathers (lane owns feature-pair; 16 loads in flight/wave; zero
// shuffles; scalar CSR/weight loads). MFMA GEMMs + fused epilogues from R5.

#define NN   65536
#define EE   524288
#define HH   128
#define NF   (NN*HH)
#define PAD  136          // LDS/Wt row stride in bf16 elems

typedef __hip_bfloat16 bf16;
typedef unsigned int   u32;
typedef unsigned short u16;
typedef __attribute__((ext_vector_type(8))) short s8v;
typedef __attribute__((ext_vector_type(4))) float f32x4;

__device__ __forceinline__ float b2f(bf16 v){ return __bfloat162float(v); }
__device__ __forceinline__ bf16  f2b(float v){ return __float2bfloat16(v); }
__device__ __forceinline__ float lo2f(u32 u){ return __uint_as_float(u<<16); }
__device__ __forceinline__ float hi2f(u32 u){ return __uint_as_float(u & 0xffff0000u); }
__device__ __forceinline__ u32 pack2(float a, float b){
  bf16 ba = f2b(a), bb = f2b(b);
  u16 ua = *reinterpret_cast<u16*>(&ba);
  u16 ub = *reinterpret_cast<u16*>(&bb);
  return ((u32)ub<<16) | (u32)ua;
}
__device__ __forceinline__ unsigned fenc(float f){ unsigned u=__float_as_uint(f); return (u&0x80000000u)?~u:(u|0x80000000u); }
__device__ __forceinline__ float fdec(unsigned u){ return __uint_as_float((u&0x80000000u)?(u&0x7fffffffu):~u); }
__device__ __forceinline__ float ldf(const void* p, size_t i, int isbf){
  return isbf ? b2f(((const bf16*)p)[i]) : ((const float*)p)[i];
}

// scal: 0 sumx,1 sumx2,2 sumd,3 sumd2,4 zc,5 sumew,6 attnmax-enc,7 attnsumexp,
//       8 probemax-enc,9 dtype flag,10..14 g,15..17 wsc

__global__ void k_fill(float* p, float v, int n){
  int i = blockIdx.x*blockDim.x + threadIdx.x;
  if (i < n) p[i] = v;
}
__global__ void k_sentinel(u16* p, int n){
  int i = blockIdx.x*blockDim.x + threadIdx.x;
  if (i < n) p[i] = 0x4640;
}
__global__ void k_init(float* scal){
  int i = threadIdx.x;
  if (i < 32) scal[i] = 0.f;
  if (i == 6) ((unsigned*)scal)[6] = 0x007fffffu;
  if (i == 8) ((unsigned*)scal)[8] = 0x80000000u;
}
__global__ void k_init_attn(float* scal){
  if (threadIdx.x==0){ ((unsigned*)scal)[6] = 0x007fffffu; scal[7] = 0.f; }
}

// dtype probe over edge_weight interpreted as bf16
__global__ void k_probe(const uint4* __restrict__ ew4, float* scal){
  __shared__ float red[4];
  int i = blockIdx.x*256 + threadIdx.x;
  uint4 v = ew4[i];
  float m = 0.f;
  u32 ws[4] = {v.x, v.y, v.z, v.w};
  #pragma unroll
  for (int q=0;q<4;++q){
    float a = lo2f(ws[q]), b = hi2f(ws[q]);
    a = isfinite(a) ? fabsf(a) : 1e30f;
    b = isfinite(b) ? fabsf(b) : 1e30f;
    m = fmaxf(m, fmaxf(a,b));
  }
  for (int o=32;o;o>>=1) m = fmaxf(m, __shfl_down(m, o, 64));
  if ((threadIdx.x&63)==0) red[threadIdx.x>>6] = m;
  __syncthreads();
  if (threadIdx.x==0){
    m = fmaxf(fmaxf(red[0],red[1]), fmaxf(red[2],red[3]));
    atomicMax((unsigned*)scal + 8, fenc(m));
  }
}
__global__ void k_flag(float* scal){
  if (threadIdx.x==0){
    float m = fdec(((const unsigned*)scal)[8]);
    scal[9] = (m < 64.f) ? 1.f : 0.f;
  }
}

// CSR build: p=r*8+slot
__global__ void k_csr(const int* __restrict__ row, const int* __restrict__ col,
                      const void* __restrict__ ew, int* cnt,
                      int* __restrict__ colS, float* __restrict__ wS, const float* scal){
  int isbf = scal[9] > 0.5f;
  int e = blockIdx.x*blockDim.x + threadIdx.x;
  int r = row[e];
  float w = ldf(ew, e, isbf);
  int slot = atomicAdd(&cnt[r], 1) & 7;
  int p = r*8 + slot;
  colS[p] = col[e];
  wS[p] = w;
}

// per-node arrays + block-reduced stats
__global__ void k_node(const int* __restrict__ cnt, const float* __restrict__ wS,
                       float* deg, float* degw, float* dis, float* scal){
  __shared__ float red[4][4];
  int i = blockIdx.x*256 + threadIdx.x;
  float dd = (float)cnt[i];
  const float4* w4 = (const float4*)(wS + i*8);
  float4 wa = w4[0], wb = w4[1];
  float s = wa.x+wa.y+wa.z+wa.w + wb.x+wb.y+wb.z+wb.w;
  deg[i] = dd; degw[i] = s;
  dis[i] = (dd>0.f) ? (1.f/sqrtf(dd)) : 1e8f;
  float d = dd, d2 = dd*dd, z = (dd==0.f)?1.f:0.f, sw = s;
  for (int o=32;o;o>>=1){
    d += __shfl_down(d,o,64); d2 += __shfl_down(d2,o,64);
    z += __shfl_down(z,o,64); sw += __shfl_down(sw,o,64);
  }
  int wv = threadIdx.x>>6;
  if ((threadIdx.x&63)==0){ red[wv][0]=d; red[wv][1]=d2; red[wv][2]=z; red[wv][3]=sw; }
  __syncthreads();
  if (threadIdx.x==0){
    float a0=0,a1=0,a2=0,a3=0;
    for (int w=0;w<4;++w){ a0+=red[w][0]; a1+=red[w][1]; a2+=red[w][2]; a3+=red[w][3]; }
    atomicAdd(&scal[2],a0); atomicAdd(&scal[3],a1);
    atomicAdd(&scal[4],a2); atomicAdd(&scal[5],a3);
  }
}

// x stats: 512 blocks, vectorized, 2 atomics/block
__global__ void k_x_stats(const void* __restrict__ x, float* scal){
  __shared__ float red[4][2];
  int isbf = scal[9] > 0.5f;
  float s=0.f, s2=0.f;
  int gtid = blockIdx.x*256 + threadIdx.x;
  if (isbf){
    const uint4* p = (const uint4*)x;
    for (int i = gtid; i < NF/8; i += 512*256){
      uint4 v = p[i];
      u32 ws[4] = {v.x,v.y,v.z,v.w};
      #pragma unroll
      for (int q=0;q<4;++q){
        float a=lo2f(ws[q]), b=hi2f(ws[q]);
        s += a+b; s2 += a*a + b*b;
      }
    }
  } else {
    const float4* p = (const float4*)x;
    for (int i = gtid; i < NF/4; i += 512*256){
      float4 v = p[i];
      s += v.x+v.y+v.z+v.w;
      s2 += v.x*v.x + v.y*v.y + v.z*v.z + v.w*v.w;
    }
  }
  for (int o=32;o;o>>=1){ s += __shfl_down(s,o,64); s2 += __shfl_down(s2,o,64); }
  int wv = threadIdx.x>>6;
  if ((threadIdx.x&63)==0){ red[wv][0]=s; red[wv][1]=s2; }
  __syncthreads();
  if (threadIdx.x==0){
    float a0=0,a1=0;
    for (int w=0;w<4;++w){ a0+=red[w][0]; a1+=red[w][1]; }
    atomicAdd(&scal[0],a0); atomicAdd(&scal[1],a1);
  }
}

__global__ void k_ctrl(float* __restrict__ scal, const void* __restrict__ prev,
                       const void* __restrict__ w1, const void* __restrict__ b1,
                       const void* __restrict__ w2, const void* __restrict__ b2,
                       const void* __restrict__ mbias, const void* __restrict__ gum,
                       const void* __restrict__ scw){
  __shared__ float in[136];
  __shared__ float hid[128];
  __shared__ float logits[5];
  int isbf = scal[9] > 0.5f;
  int t = threadIdx.x;
  if (t == 0){
    float sumx=scal[0], sumx2=scal[1], sumd=scal[2], sumd2=scal[3], zc=scal[4], sumew=scal[5];
    float Mf = (float)NF;
    in[0] = (float)NN/1000.f;
    in[1] = (float)EE/(float)NN;
    float vard = (sumd2 - sumd*sumd/(float)NN) / ((float)NN - 1.f);
    in[2] = sqrtf(fmaxf(vard, 0.f));
    in[3] = zc / (float)NN;
    in[4] = sumx / Mf;
    float varx = (sumx2 - sumx*sumx/Mf) / (Mf - 1.f);
    in[5] = sqrtf(fmaxf(varx, 0.f));
    in[6] = sumew / (float)EE;
    in[7] = (float)EE / ((float)NN*(float)NN);
  }
  in[8+t] = ldf(prev, t, isbf);
  __syncthreads();
  float a = ldf(b1, t, isbf);
  for (int i=0;i<136;++i) a += in[i]*ldf(w1, (size_t)i*128+t, isbf);
  hid[t] = fmaxf(a, 0.f);
  __syncthreads();
  if (t < 5){
    float l = ldf(b2, t, isbf);
    for (int j=0;j<128;++j) l += hid[j]*ldf(w2, (size_t)j*5+t, isbf);
    l += ldf(mbias, t, isbf);
    logits[t] = (l + ldf(gum, t, isbf)) * 2.0f;   // /TAU, TAU=0.5
  }
  __syncthreads();
  if (t == 0){
    float m=-1e30f; for (int i=0;i<5;++i) m=fmaxf(m,logits[i]);
    float p[5], s=0.f;
    for (int i=0;i<5;++i){ p[i]=expf(logits[i]-m); s+=p[i]; }
    for (int i=0;i<5;++i){ float pr=p[i]/s; scal[10+i] = (pr>0.001f)?pr:0.f; }
    float sw[3]; float mw=-1e30f;
    for (int i=0;i<3;++i){ sw[i]=ldf(scw,i,isbf); mw=fmaxf(mw,sw[i]); }
    float ss=0.f; for (int i=0;i<3;++i){ sw[i]=expf(sw[i]-mw); ss+=sw[i]; }
    for (int i=0;i<3;++i) scal[15+i]=sw[i]/ss;
  }
}

// ---- weight transposes: W[k][n] -> Wt[n*PAD + k] bf16 ----
__global__ void k_wt10(const void* w0,const void* w1,const void* w2,const void* w3,const void* w4,
                       bf16* dst, const float* fl){
  int isbf = fl[0]>0.5f;
  int idx = blockIdx.x*256 + threadIdx.x;
  if (idx >= 10*128*PAD) return;
  int wsel = idx/(128*PAD), within = idx%(128*PAD);
  int n = within/PAD, k = within%PAD;
  const void* w = wsel<2?w0: wsel<4?w1: wsel<6?w2: wsel<8?w3: w4;
  size_t lay = (size_t)(wsel&1)*16384;
  float v = (k<128) ? ldf(w, lay + (size_t)k*128 + n, isbf) : 0.f;
  dst[idx] = f2b(v);
}
__global__ void k_wt(const void* W, int K, int Nout, bf16* dst, const float* fl){
  int isbf = fl[0]>0.5f;
  int idx = blockIdx.x*256 + threadIdx.x;
  if (idx >= Nout*PAD) return;
  int n = idx/PAD, k = idx%PAD;
  float v = (k<K) ? ldf(W, (size_t)k*Nout + n, isbf) : 0.f;
  dst[idx] = f2b(v);
}
__global__ void k_wt_cat(const void* aw1, const void* ab1, bf16* dst, bf16* bcat,
                         const float* fl){
  int isbf = fl[0]>0.5f;
  int idx = blockIdx.x*256 + threadIdx.x;
  if (idx >= 128*PAD) return;
  int n = idx/PAD, k = idx%PAD;
  float v = 0.f;
  if (k < 128) v = (n<64) ? ldf(aw1, (size_t)k*64 + n, isbf)
                          : ldf(aw1, (size_t)(128+k)*64 + (n-64), isbf);
  dst[idx] = f2b(v);
  if (idx < 128) bcat[idx] = f2b(idx<64 ? ldf(ab1, idx, isbf) : 0.f);
}

// ---- MFMA GEMM: 64 rows/block, 16x16x32 bf16 ----
__global__ __launch_bounds__(256) void k_mgemm(
    const void* __restrict__ Aext, const bf16* __restrict__ Ab,
    const float* __restrict__ Af, int K,
    const bf16* __restrict__ Wt, const void* __restrict__ bias, int Boff, int Nout,
    bf16* __restrict__ outB, float* __restrict__ outF, void* __restrict__ outE,
    const void* __restrict__ ts, int act, int bbf, const float* __restrict__ fl){
  __shared__ bf16 sA[64*PAD];
  __shared__ bf16 sW[128*PAD];
  int flA = fl[0] > 0.5f;
  int tid = threadIdx.x;
  int rowBase = blockIdx.x*64;
  {
    int tot = (Nout*PAD)/8;
    const uint4* src = (const uint4*)Wt;
    uint4* dst = (uint4*)sW;
    for (int i = tid; i < tot; i += 256) dst[i] = src[i];
  }
  {
    int kc = K/8;
    for (int i = tid; i < 64*kc; i += 256){
      int m = i/kc, c = i - m*kc;
      size_t gi = (size_t)(rowBase+m)*K + (size_t)c*8;
      uint4 v;
      if (Ab) v = *(const uint4*)(Ab+gi);
      else if (Af){
        float4 f0 = *(const float4*)(Af+gi);
        float4 f1 = *(const float4*)(Af+gi+4);
        v.x=pack2(f0.x,f0.y); v.y=pack2(f0.z,f0.w); v.z=pack2(f1.x,f1.y); v.w=pack2(f1.z,f1.w);
      } else if (flA) v = *(const uint4*)((const bf16*)Aext+gi);
      else {
        const float* Ax = (const float*)Aext;
        float4 f0 = *(const float4*)(Ax+gi);
        float4 f1 = *(const float4*)(Ax+gi+4);
        v.x=pack2(f0.x,f0.y); v.y=pack2(f0.z,f0.w); v.z=pack2(f1.x,f1.y); v.w=pack2(f1.z,f1.w);
      }
      *(uint4*)&sA[m*PAD + c*8] = v;
    }
  }
  __syncthreads();
  int wave = tid>>6, lane = tid&63;
  int m0 = wave*16;
  int l15 = lane&15, quad = lane>>4;
  int ntiles = Nout>>4, ksteps = K>>5;
  f32x4 acc[8];
  #pragma unroll
  for (int t=0;t<8;++t) acc[t] = (f32x4){0.f,0.f,0.f,0.f};
  for (int ks=0; ks<ksteps; ++ks){
    int kb = ks*32 + quad*8;
    s8v af = *(const s8v*)&sA[(m0 + l15)*PAD + kb];
    for (int t=0;t<ntiles;++t){
      s8v bfr = *(const s8v*)&sW[(t*16 + l15)*PAD + kb];
      acc[t] = __builtin_amdgcn_mfma_f32_16x16x32_bf16(af, bfr, acc[t], 0, 0, 0);
    }
  }
  int isbfB = bbf || flA;
  for (int t=0;t<ntiles;++t){
    int colN = t*16 + l15;
    float bv = isbfB ? b2f(((const bf16*)bias)[Boff+colN]) : ((const float*)bias)[Boff+colN];
    float w128 = ts ? b2f(sW[colN*PAD + K]) : 0.f;
    #pragma unroll
    for (int r=0;r<4;++r){
      int rowG = rowBase + m0 + quad*4 + r;
      float v = acc[t][r] + bv;
      if (ts) v += (flA ? b2f(((const bf16*)ts)[rowG]) : ((const float*)ts)[rowG]) * w128;
      if (act) v = fmaxf(v, 0.f);
      size_t oi = (size_t)rowG*Nout + colN;
      if (outB) outB[oi] = f2b(v);
      else if (outF) outF[oi] = v;
      else if (flA) ((bf16*)outE)[oi] = f2b(v);
      else ((float*)outE)[oi] = v;
    }
  }
}

// ---- CSR gather v3: lane owns a feature-pair (u32), scalar row bases ----
// wave = 2 nodes; 16 coalesced dword gathers in flight; zero shuffles.
// modes: 0 spatial, 1 temporal, 2 attn, 3 diffusion, 4 hier-mid, 5 hier-final
// flags: 1 first-heat, 2 finalize(mode3), 4 accum->acc2, 8 accum-first
__global__ __launch_bounds__(256) void g_aggv(
    const bf16* __restrict__ Hin, bf16* __restrict__ out, bf16* __restrict__ hout,
    bf16* __restrict__ acc2,
    const int* __restrict__ colS, const float* __restrict__ wS,
    const float* __restrict__ escS,
    const float* __restrict__ degv, const float* __restrict__ dis,
    const void* __restrict__ heat, int hidx, int mode, int flags, int gidx,
    const float* __restrict__ scal){
  int tid = threadIdx.x;
  int lf = tid & 63;
  int wave = tid >> 6;
  int rr = __builtin_amdgcn_readfirstlane((blockIdx.x*4 + wave)*2);
  const u32* H32 = (const u32*)Hin;
  u32* out32 = (u32*)out;
  u32* ho32 = (u32*)hout;
  u32* ac32 = (u32*)acc2;
  float inv = (mode==2) ? 1.f/fmaxf(scal[7], 1e-30f) : 0.f;
  float tt  = (mode==3) ? ldf(heat, hidx, scal[9]>0.5f) : 0.f;
  float g = scal[10+gidx];
  float w0s=scal[15], w1s=scal[16], w2s=scal[17];

  u32 ld[2][8];
  float wgt[2][8];
  #pragma unroll
  for (int n=0;n<2;++n){
    int rn = rr + n;
    #pragma unroll
    for (int s=0;s<8;++s){
      int c = colS[rn*8+s];                 // scalar (s_load)
      ld[n][s] = (H32 + (size_t)c*64)[lf];  // coalesced dword, scalar base
      float w = 1.f;
      if (mode==0)      w = wS[rn*8+s];
      else if (mode==2) w = escS[rn*8+s]*inv;
      else if (mode==3) w = dis[rn]*dis[c];
      wgt[n][s] = w;
    }
  }
  float aclo[2] = {0.f,0.f}, achi[2] = {0.f,0.f};
  #pragma unroll
  for (int n=0;n<2;++n)
    #pragma unroll
    for (int s=0;s<8;++s){
      aclo[n] += wgt[n][s]*lo2f(ld[n][s]);
      achi[n] += wgt[n][s]*hi2f(ld[n][s]);
    }

  #pragma unroll
  for (int n=0;n<2;++n){
    int rn = rr + n;
    size_t rb = (size_t)rn*64 + lf;
    float vlo, vhi;
    if (mode==0){
      float rd = 1.f/fmaxf(degv[rn], 1.f);
      vlo = fmaxf(aclo[n]*rd, 0.f); vhi = fmaxf(achi[n]*rd, 0.f);
    } else if (mode==1){
      float rd = 1.f/fmaxf(degv[rn], 1.f);
      u32 gv = out32[rb];
      u32 hv = H32[rb];
      float s0 = 1.f/(1.f+expf(-lo2f(gv)));
      float s1 = 1.f/(1.f+expf(-hi2f(gv)));
      vlo = fmaxf(s0*lo2f(hv) + (1.f-s0)*aclo[n]*rd, 0.f);
      vhi = fmaxf(s1*hi2f(hv) + (1.f-s1)*achi[n]*rd, 0.f);
    } else if (mode==2){
      vlo = fmaxf(aclo[n], 0.f); vhi = fmaxf(achi[n], 0.f);
    } else if (mode==3){
      u32 hv = H32[rb];
      float hlo = (1.f-tt)*lo2f(hv) + tt*aclo[n];
      float hhi = (1.f-tt)*hi2f(hv) + tt*achi[n];
      if (!(flags&2)) ho32[rb] = pack2(hlo, hhi);
      if (flags&1){ vlo = hlo; vhi = hhi; }
      else { u32 pv = out32[rb]; vlo = lo2f(pv)+hlo; vhi = hi2f(pv)+hhi; }
      if (flags&2){ vlo = fmaxf(0.2f*vlo, 0.f); vhi = fmaxf(0.2f*vhi, 0.f); }
    } else if (mode==4){
      float rd = 1.f/fmaxf(degv[rn], 1.f);
      vlo = aclo[n]*rd; vhi = achi[n]*rd;
    } else { // 5: h1 in hout, h2 = Hin row, h3 = acc/d
      float rd = 1.f/fmaxf(degv[rn], 1.f);
      u32 a1 = ho32[rb];
      u32 a2 = H32[rb];
      vlo = fmaxf(w0s*lo2f(a1) + w1s*lo2f(a2) + w2s*aclo[n]*rd, 0.f);
      vhi = fmaxf(w0s*hi2f(a1) + w1s*hi2f(a2) + w2s*achi[n]*rd, 0.f);
    }
    out32[rb] = pack2(vlo, vhi);
    if (flags&4){
      float alo = g*vlo, ahi = g*vhi;
      if (!(flags&8)){ u32 bv = ac32[rb]; alo += lo2f(bv); ahi += hi2f(bv); }
      ac32[rb] = pack2(alo, ahi);
    }
  }
}

// ---- edge scores: wave per node (8 edges), 8 lanes/edge ----
__global__ __launch_bounds__(256) void k_edge_score4(
    const float* __restrict__ Huv, const int* __restrict__ colS,
    const void* __restrict__ aw2, const void* __restrict__ ab2,
    float* __restrict__ escS, const float* __restrict__ fl){
  int isbf = fl[0] > 0.5f;
  int tid = threadIdx.x;
  int r = blockIdx.x*4 + (tid>>6);
  int lane = tid & 63;
  int ef = lane>>3, ff = lane&7;
  int p = r*8 + ef;
  int c = colS[p];
  const float* up = Huv + (size_t)r*128 + ff*8;
  const float* vp = Huv + (size_t)c*128 + 64 + ff*8;
  float4 u0 = *(const float4*)up,     u1 = *(const float4*)(up+4);
  float4 v0 = *(const float4*)vp,     v1 = *(const float4*)(vp+4);
  float w2v[8];
  if (isbf){
    const bf16* a2 = (const bf16*)aw2 + ff*8;
    uint4 t4 = *(const uint4*)a2;
    u32 tw[4]={t4.x,t4.y,t4.z,t4.w};
    #pragma unroll
    for (int q=0;q<4;++q){ w2v[2*q]=lo2f(tw[q]); w2v[2*q+1]=hi2f(tw[q]); }
  } else {
    const float* a2 = (const float*)aw2 + ff*8;
    float4 f0 = *(const float4*)a2, f1 = *(const float4*)(a2+4);
    w2v[0]=f0.x; w2v[1]=f0.y; w2v[2]=f0.z; w2v[3]=f0.w;
    w2v[4]=f1.x; w2v[5]=f1.y; w2v[6]=f1.z; w2v[7]=f1.w;
  }
  float s = 0.f;
  s += fmaxf(u0.x+v0.x,0.f)*w2v[0];
  s += fmaxf(u0.y+v0.y,0.f)*w2v[1];
  s += fmaxf(u0.z+v0.z,0.f)*w2v[2];
  s += fmaxf(u0.w+v0.w,0.f)*w2v[3];
  s += fmaxf(u1.x+v1.x,0.f)*w2v[4];
  s += fmaxf(u1.y+v1.y,0.f)*w2v[5];
  s += fmaxf(u1.z+v1.z,0.f)*w2v[6];
  s += fmaxf(u1.w+v1.w,0.f)*w2v[7];
  s += __shfl_xor(s, 1, 64);
  s += __shfl_xor(s, 2, 64);
  s += __shfl_xor(s, 4, 64);
  if (ff == 0) escS[p] = s + ldf(ab2, 0, isbf);
}

// global softmax over E scores
__global__ void k_score_max(const float4* __restrict__ sc4, float* scal){
  __shared__ float red[4];
  float m = -1e30f;
  for (int i = blockIdx.x*256 + threadIdx.x; i < EE/4; i += 256*256){
    float4 v = sc4[i];
    m = fmaxf(fmaxf(m, fmaxf(v.x,v.y)), fmaxf(v.z,v.w));
  }
  for (int o=32;o;o>>=1) m = fmaxf(m, __shfl_down(m, o, 64));
  if ((threadIdx.x&63)==0) red[threadIdx.x>>6] = m;
  __syncthreads();
  if (threadIdx.x==0){
    m = fmaxf(fmaxf(red[0],red[1]), fmaxf(red[2],red[3]));
    atomicMax((unsigned*)scal + 6, fenc(m));
  }
}
__global__ void k_score_exp(float4* __restrict__ sc4, float* scal){
  __shared__ float red[4];
  float mx = fdec(((const unsigned*)scal)[6]);
  float s = 0.f;
  for (int i = blockIdx.x*256 + threadIdx.x; i < EE/4; i += 256*256){
    float4 v = sc4[i];
    v.x = expf(v.x-mx); v.y = expf(v.y-mx); v.z = expf(v.z-mx); v.w = expf(v.w-mx);
    sc4[i] = v;
    s += v.x+v.y+v.z+v.w;
  }
  for (int o=32;o;o>>=1) s += __shfl_down(s, o, 64);
  if ((threadIdx.x&63)==0) red[threadIdx.x>>6] = s;
  __syncthreads();
  if (threadIdx.x==0) atomicAdd(&scal[7], red[0]+red[1]+red[2]+red[3]);
}

extern "C" void kernel_launch(void* const* d_in, const int* in_sizes, int n_in,
                              void* d_out, int out_size, void* d_ws, size_t ws_size,
                              hipStream_t stream){
  (void)in_sizes; (void)n_in;
  const void* x    = d_in[0];
  const int*  ei   = (const int*)d_in[1];
  const void* tsv  = d_in[2];
  const void* ew   = d_in[3];
  const void* prev = d_in[4];
  const void* gum  = d_in[5];
  const void* cw1  = d_in[6];
  const void* cb1  = d_in[7];
  const void* cw2  = d_in[8];
  const void* cb2  = d_in[9];
  const void* mbias= d_in[10];
  const void* aw1  = d_in[11];
  const void* ab1  = d_in[12];
  const void* aw2  = d_in[13];
  const void* ab2  = d_in[14];
  const void* heat = d_in[15];
  const void* tgw  = d_in[16];
  const void* tgb  = d_in[17];
  const void* scw  = d_in[18];
  const void* spw  = d_in[19];
  const void* spb  = d_in[20];
  const void* tww  = d_in[21];
  const void* twb  = d_in[22];
  const void* atw  = d_in[23];
  const void* atb  = d_in[24];
  const void* diw  = d_in[25];
  const void* dib  = d_in[26];
  const void* hiw  = d_in[27];
  const void* hib  = d_in[28];
  const void* ow1  = d_in[29];
  const void* ob1  = d_in[30];
  const void* ow2  = d_in[31];
  const void* ob2  = d_in[32];
  const int* row = ei, *col = ei + EE;

  const size_t WT10 = 10*128*PAD, WTE = 128*PAD, WTO = 64*PAD;
  size_t need = (size_t)NF*2*4 + (size_t)EE*4*3 + (size_t)NN*4*4
              + (WT10 + WTE*2 + WTO*2 + 128)*2 + 256;
  if (ws_size < need){
    k_sentinel<<<(out_size+255)/256,256,0,stream>>>((u16*)d_out, out_size);
    return;
  }
  bf16* Hb   = (bf16*)d_ws;
  bf16* Hb2  = Hb + (size_t)NF;
  bf16* B1   = Hb2 + (size_t)NF;
  bf16* B2   = B1 + (size_t)NF;
  float* escS= (float*)(B2 + (size_t)NF);
  int*   colS= (int*)(escS + EE);
  float* wS  = (float*)(colS + EE);
  int*   cnt = (int*)(wS + EE);
  float* deg = (float*)(cnt + NN);
  float* degw= deg + NN;
  float* dis = degw + NN;
  bf16* wt_l = (bf16*)(dis + NN);      // 10 layers: sp0,sp1,tw0,tw1,at0,at1,di0,di1,hi0,hi1
  bf16* wt_tg= wt_l + WT10;
  bf16* wt_ct= wt_tg + WTE;
  bf16* wt_o1= wt_ct + WTE;
  bf16* wt_o2= wt_o1 + WTO;
  bf16* bcat = wt_o2 + WTO;
  float* scal= (float*)(bcat + 128);
  const float* fl = scal + 9;
  float* Huv = (float*)Hb2;            // fp32 N*128 overlay (Hb2+B1) during attention

  const int TB = 256;
  const int GAG = NN/8;                // g_aggv: 4 waves x 2 nodes per block
  const int GMM = NN/64;

  // ---- prologue ----
  k_init<<<1,64,0,stream>>>(scal);
  k_probe<<<EE/8/TB,TB,0,stream>>>((const uint4*)ew, scal);
  k_flag<<<1,64,0,stream>>>(scal);
  k_wt10<<<(10*128*PAD+TB-1)/TB,TB,0,stream>>>(spw, tww, atw, diw, hiw, wt_l, fl);
  k_wt<<<(128*PAD+TB-1)/TB,TB,0,stream>>>(tgw, 129, 128, wt_tg, fl);
  k_wt<<<(64*PAD+TB-1)/TB,TB,0,stream>>>(ow1, 128, 64, wt_o1, fl);
  k_wt<<<(64*PAD+TB-1)/TB,TB,0,stream>>>(ow2, 64, 64, wt_o2, fl);
  k_wt_cat<<<(128*PAD+TB-1)/TB,TB,0,stream>>>(aw1, ab1, wt_ct, bcat, fl);
  k_fill<<<NN/TB,TB,0,stream>>>((float*)cnt, 0.f, NN);
  k_csr<<<EE/TB,TB,0,stream>>>(row, col, ew, cnt, colS, wS, scal);
  k_node<<<NN/TB,TB,0,stream>>>(cnt, wS, deg, degw, dis, scal);
  k_x_stats<<<512,TB,0,stream>>>(x, scal);
  k_ctrl<<<1,128,0,stream>>>(scal, prev, cw1, cb1, cw2, cb2, mbias, gum, scw);

  auto mgemm = [&](const void* Aext, const bf16* Ab, const float* Af, int K,
                   const bf16* Wt, const void* B, int Boff, int Nout,
                   bf16* oB, float* oF, void* oE, const void* tsp, int act, int bbf){
    k_mgemm<<<GMM, TB, 0, stream>>>(Aext, Ab, Af, K, Wt, B, Boff, Nout,
                                    oB, oF, oE, tsp, act, bbf, fl);
  };
  auto agg = [&](const bf16* Hin, bf16* out, bf16* ho, int mode, int flags,
                 int gidx, const float* dv, int hidx){
    g_aggv<<<GAG, TB, 0, stream>>>(Hin, out, ho, B2, colS, wS, escS, dv, dis,
                                   heat, hidx, mode, flags, gidx, scal);
  };

  // ---- spatial (g0): state B1 ----
  for (int i=0;i<2;++i){
    mgemm(i?nullptr:x, i?B1:nullptr, nullptr, 128, wt_l + (size_t)i*WTE, spb, i*128, 128,
          Hb, nullptr, nullptr, nullptr, 0, 0);
    agg(Hb, B1, nullptr, 0, i?(4|8):0, 0, degw, 0);
  }

  // ---- temporal (g1) ----
  for (int i=0;i<2;++i){
    mgemm(i?nullptr:x, i?B1:nullptr, nullptr, 128, wt_l + (size_t)(2+i)*WTE, twb, i*128, 128,
          Hb, nullptr, nullptr, nullptr, 0, 0);
    mgemm(nullptr, Hb, nullptr, 128, wt_tg, tgb, 0, 128,
          B1, nullptr, nullptr, tsv, 0, 0);                 // gate preact -> B1
    agg(Hb, B1, nullptr, 1, i?4:0, 1, deg, 0);
  }

  // ---- attention (g2) ----
  for (int i=0;i<2;++i){
    mgemm(i?nullptr:x, i?B1:nullptr, nullptr, 128, wt_l + (size_t)(4+i)*WTE, atb, i*128, 128,
          Hb, nullptr, nullptr, nullptr, 0, 0);
    mgemm(nullptr, Hb, nullptr, 128, wt_ct, bcat, 0, 128,
          nullptr, Huv, nullptr, nullptr, 0, 1);            // Huv fp32
    k_edge_score4<<<NN/4,TB,0,stream>>>(Huv, colS, aw2, ab2, escS, fl);
    k_init_attn<<<1,64,0,stream>>>(scal);
    k_score_max<<<256,TB,0,stream>>>((const float4*)escS, scal);
    k_score_exp<<<256,TB,0,stream>>>((float4*)escS, scal);
    agg(Hb, B1, nullptr, 2, i?4:0, 2, deg, 0);
  }

  // ---- diffusion (g3) ----
  for (int i=0;i<2;++i){
    mgemm(i?nullptr:x, i?B1:nullptr, nullptr, 128, wt_l + (size_t)(6+i)*WTE, dib, i*128, 128,
          Hb, nullptr, nullptr, nullptr, 0, 0);
    bf16* hin = Hb; bf16* hot = Hb2;
    for (int j=0;j<5;++j){
      int flags = (j==0?1:0) | (j==4?2:0) | ((i==1&&j==4)?4:0);
      agg(hin, B1, hot, 3, flags, 3, deg, j);
      bf16* t = hin; hin = hot; hot = t;
    }
  }

  // ---- hierarchical (g4) ----
  for (int i=0;i<2;++i){
    mgemm(i?nullptr:x, i?B1:nullptr, nullptr, 128, wt_l + (size_t)(8+i)*WTE, hib, i*128, 128,
          Hb, nullptr, nullptr, nullptr, 0, 0);
    agg(Hb,  Hb2, nullptr, 4, 0, 4, deg, 0);                // h1 -> Hb2
    agg(Hb2, Hb,  nullptr, 4, 0, 4, deg, 0);                // h2 -> Hb
    agg(Hb,  B1,  Hb2,     5, i?4:0, 4, deg, 0);            // h3+combine -> B1
  }

  // ---- output MLP ----
  mgemm(nullptr, B2, nullptr, 128, wt_o1, ob1, 0, 64,
        nullptr, (float*)Hb, nullptr, nullptr, 1, 0);
  mgemm(nullptr, nullptr, (float*)Hb, 64, wt_o2, ob2, 0, 64,
        nullptr, nullptr, d_out, nullptr, 0, 0);
}

// Round 8
// 1417.907 us; speedup vs baseline: 1.0704x; 1.0704x over previous
//
#include <hip/hip_runtime.h>
#include <hip/hip_bf16.h>
#include <math.h>

// MorphingGNN MI355X — round 7: mgemm de-staged (A direct from global via
// dwordx4 per lane — no sA LDS, no pack loop, 4 blocks/CU), W-only LDS.
// Gather (g_aggv) at measured random-256B ceiling ~2.3 TB/s, unchanged.

#define NN   65536
#define EE   524288
#define HH   128
#define NF   (NN*HH)
#define PAD  136          // Wt row stride in bf16 elems

typedef __hip_bfloat16 bf16;
typedef unsigned int   u32;
typedef unsigned short u16;
typedef __attribute__((ext_vector_type(8))) short s8v;
typedef __attribute__((ext_vector_type(4))) float f32x4;

__device__ __forceinline__ float b2f(bf16 v){ return __bfloat162float(v); }
__device__ __forceinline__ bf16  f2b(float v){ return __float2bfloat16(v); }
__device__ __forceinline__ float lo2f(u32 u){ return __uint_as_float(u<<16); }
__device__ __forceinline__ float hi2f(u32 u){ return __uint_as_float(u & 0xffff0000u); }
__device__ __forceinline__ u32 pack2(float a, float b){
  bf16 ba = f2b(a), bb = f2b(b);
  u16 ua = *reinterpret_cast<u16*>(&ba);
  u16 ub = *reinterpret_cast<u16*>(&bb);
  return ((u32)ub<<16) | (u32)ua;
}
__device__ __forceinline__ unsigned fenc(float f){ unsigned u=__float_as_uint(f); return (u&0x80000000u)?~u:(u|0x80000000u); }
__device__ __forceinline__ float fdec(unsigned u){ return __uint_as_float((u&0x80000000u)?(u&0x7fffffffu):~u); }
__device__ __forceinline__ float ldf(const void* p, size_t i, int isbf){
  return isbf ? b2f(((const bf16*)p)[i]) : ((const float*)p)[i];
}

// scal: 0 sumx,1 sumx2,2 sumd,3 sumd2,4 zc,5 sumew,6 attnmax-enc,7 attnsumexp,
//       8 probemax-enc,9 dtype flag,10..14 g,15..17 wsc

__global__ void k_fill(float* p, float v, int n){
  int i = blockIdx.x*blockDim.x + threadIdx.x;
  if (i < n) p[i] = v;
}
__global__ void k_sentinel(u16* p, int n){
  int i = blockIdx.x*blockDim.x + threadIdx.x;
  if (i < n) p[i] = 0x4640;
}
__global__ void k_init(float* scal){
  int i = threadIdx.x;
  if (i < 32) scal[i] = 0.f;
  if (i == 6) ((unsigned*)scal)[6] = 0x007fffffu;
  if (i == 8) ((unsigned*)scal)[8] = 0x80000000u;
}
__global__ void k_init_attn(float* scal){
  if (threadIdx.x==0){ ((unsigned*)scal)[6] = 0x007fffffu; scal[7] = 0.f; }
}

// dtype probe over edge_weight interpreted as bf16
__global__ void k_probe(const uint4* __restrict__ ew4, float* scal){
  __shared__ float red[4];
  int i = blockIdx.x*256 + threadIdx.x;
  uint4 v = ew4[i];
  float m = 0.f;
  u32 ws[4] = {v.x, v.y, v.z, v.w};
  #pragma unroll
  for (int q=0;q<4;++q){
    float a = lo2f(ws[q]), b = hi2f(ws[q]);
    a = isfinite(a) ? fabsf(a) : 1e30f;
    b = isfinite(b) ? fabsf(b) : 1e30f;
    m = fmaxf(m, fmaxf(a,b));
  }
  for (int o=32;o;o>>=1) m = fmaxf(m, __shfl_down(m, o, 64));
  if ((threadIdx.x&63)==0) red[threadIdx.x>>6] = m;
  __syncthreads();
  if (threadIdx.x==0){
    m = fmaxf(fmaxf(red[0],red[1]), fmaxf(red[2],red[3]));
    atomicMax((unsigned*)scal + 8, fenc(m));
  }
}
__global__ void k_flag(float* scal){
  if (threadIdx.x==0){
    float m = fdec(((const unsigned*)scal)[8]);
    scal[9] = (m < 64.f) ? 1.f : 0.f;
  }
}

// CSR build: p=r*8+slot
__global__ void k_csr(const int* __restrict__ row, const int* __restrict__ col,
                      const void* __restrict__ ew, int* cnt,
                      int* __restrict__ colS, float* __restrict__ wS, const float* scal){
  int isbf = scal[9] > 0.5f;
  int e = blockIdx.x*blockDim.x + threadIdx.x;
  int r = row[e];
  float w = ldf(ew, e, isbf);
  int slot = atomicAdd(&cnt[r], 1) & 7;
  int p = r*8 + slot;
  colS[p] = col[e];
  wS[p] = w;
}

// per-node arrays + block-reduced stats
__global__ void k_node(const int* __restrict__ cnt, const float* __restrict__ wS,
                       float* deg, float* degw, float* dis, float* scal){
  __shared__ float red[4][4];
  int i = blockIdx.x*256 + threadIdx.x;
  float dd = (float)cnt[i];
  const float4* w4 = (const float4*)(wS + i*8);
  float4 wa = w4[0], wb = w4[1];
  float s = wa.x+wa.y+wa.z+wa.w + wb.x+wb.y+wb.z+wb.w;
  deg[i] = dd; degw[i] = s;
  dis[i] = (dd>0.f) ? (1.f/sqrtf(dd)) : 1e8f;
  float d = dd, d2 = dd*dd, z = (dd==0.f)?1.f:0.f, sw = s;
  for (int o=32;o;o>>=1){
    d += __shfl_down(d,o,64); d2 += __shfl_down(d2,o,64);
    z += __shfl_down(z,o,64); sw += __shfl_down(sw,o,64);
  }
  int wv = threadIdx.x>>6;
  if ((threadIdx.x&63)==0){ red[wv][0]=d; red[wv][1]=d2; red[wv][2]=z; red[wv][3]=sw; }
  __syncthreads();
  if (threadIdx.x==0){
    float a0=0,a1=0,a2=0,a3=0;
    for (int w=0;w<4;++w){ a0+=red[w][0]; a1+=red[w][1]; a2+=red[w][2]; a3+=red[w][3]; }
    atomicAdd(&scal[2],a0); atomicAdd(&scal[3],a1);
    atomicAdd(&scal[4],a2); atomicAdd(&scal[5],a3);
  }
}

// x stats: 512 blocks, vectorized, 2 atomics/block
__global__ void k_x_stats(const void* __restrict__ x, float* scal){
  __shared__ float red[4][2];
  int isbf = scal[9] > 0.5f;
  float s=0.f, s2=0.f;
  int gtid = blockIdx.x*256 + threadIdx.x;
  if (isbf){
    const uint4* p = (const uint4*)x;
    for (int i = gtid; i < NF/8; i += 512*256){
      uint4 v = p[i];
      u32 ws[4] = {v.x,v.y,v.z,v.w};
      #pragma unroll
      for (int q=0;q<4;++q){
        float a=lo2f(ws[q]), b=hi2f(ws[q]);
        s += a+b; s2 += a*a + b*b;
      }
    }
  } else {
    const float4* p = (const float4*)x;
    for (int i = gtid; i < NF/4; i += 512*256){
      float4 v = p[i];
      s += v.x+v.y+v.z+v.w;
      s2 += v.x*v.x + v.y*v.y + v.z*v.z + v.w*v.w;
    }
  }
  for (int o=32;o;o>>=1){ s += __shfl_down(s,o,64); s2 += __shfl_down(s2,o,64); }
  int wv = threadIdx.x>>6;
  if ((threadIdx.x&63)==0){ red[wv][0]=s; red[wv][1]=s2; }
  __syncthreads();
  if (threadIdx.x==0){
    float a0=0,a1=0;
    for (int w=0;w<4;++w){ a0+=red[w][0]; a1+=red[w][1]; }
    atomicAdd(&scal[0],a0); atomicAdd(&scal[1],a1);
  }
}

__global__ void k_ctrl(float* __restrict__ scal, const void* __restrict__ prev,
                       const void* __restrict__ w1, const void* __restrict__ b1,
                       const void* __restrict__ w2, const void* __restrict__ b2,
                       const void* __restrict__ mbias, const void* __restrict__ gum,
                       const void* __restrict__ scw){
  __shared__ float in[136];
  __shared__ float hid[128];
  __shared__ float logits[5];
  int isbf = scal[9] > 0.5f;
  int t = threadIdx.x;
  if (t == 0){
    float sumx=scal[0], sumx2=scal[1], sumd=scal[2], sumd2=scal[3], zc=scal[4], sumew=scal[5];
    float Mf = (float)NF;
    in[0] = (float)NN/1000.f;
    in[1] = (float)EE/(float)NN;
    float vard = (sumd2 - sumd*sumd/(float)NN) / ((float)NN - 1.f);
    in[2] = sqrtf(fmaxf(vard, 0.f));
    in[3] = zc / (float)NN;
    in[4] = sumx / Mf;
    float varx = (sumx2 - sumx*sumx/Mf) / (Mf - 1.f);
    in[5] = sqrtf(fmaxf(varx, 0.f));
    in[6] = sumew / (float)EE;
    in[7] = (float)EE / ((float)NN*(float)NN);
  }
  in[8+t] = ldf(prev, t, isbf);
  __syncthreads();
  float a = ldf(b1, t, isbf);
  for (int i=0;i<136;++i) a += in[i]*ldf(w1, (size_t)i*128+t, isbf);
  hid[t] = fmaxf(a, 0.f);
  __syncthreads();
  if (t < 5){
    float l = ldf(b2, t, isbf);
    for (int j=0;j<128;++j) l += hid[j]*ldf(w2, (size_t)j*5+t, isbf);
    l += ldf(mbias, t, isbf);
    logits[t] = (l + ldf(gum, t, isbf)) * 2.0f;   // /TAU, TAU=0.5
  }
  __syncthreads();
  if (t == 0){
    float m=-1e30f; for (int i=0;i<5;++i) m=fmaxf(m,logits[i]);
    float p[5], s=0.f;
    for (int i=0;i<5;++i){ p[i]=expf(logits[i]-m); s+=p[i]; }
    for (int i=0;i<5;++i){ float pr=p[i]/s; scal[10+i] = (pr>0.001f)?pr:0.f; }
    float sw[3]; float mw=-1e30f;
    for (int i=0;i<3;++i){ sw[i]=ldf(scw,i,isbf); mw=fmaxf(mw,sw[i]); }
    float ss=0.f; for (int i=0;i<3;++i){ sw[i]=expf(sw[i]-mw); ss+=sw[i]; }
    for (int i=0;i<3;++i) scal[15+i]=sw[i]/ss;
  }
}

// ---- weight transposes: W[k][n] -> Wt[n*PAD + k] bf16 ----
__global__ void k_wt10(const void* w0,const void* w1,const void* w2,const void* w3,const void* w4,
                       bf16* dst, const float* fl){
  int isbf = fl[0]>0.5f;
  int idx = blockIdx.x*256 + threadIdx.x;
  if (idx >= 10*128*PAD) return;
  int wsel = idx/(128*PAD), within = idx%(128*PAD);
  int n = within/PAD, k = within%PAD;
  const void* w = wsel<2?w0: wsel<4?w1: wsel<6?w2: wsel<8?w3: w4;
  size_t lay = (size_t)(wsel&1)*16384;
  float v = (k<128) ? ldf(w, lay + (size_t)k*128 + n, isbf) : 0.f;
  dst[idx] = f2b(v);
}
__global__ void k_wt(const void* W, int K, int Nout, bf16* dst, const float* fl){
  int isbf = fl[0]>0.5f;
  int idx = blockIdx.x*256 + threadIdx.x;
  if (idx >= Nout*PAD) return;
  int n = idx/PAD, k = idx%PAD;
  float v = (k<K) ? ldf(W, (size_t)k*Nout + n, isbf) : 0.f;
  dst[idx] = f2b(v);
}
__global__ void k_wt_cat(const void* aw1, const void* ab1, bf16* dst, bf16* bcat,
                         const float* fl){
  int isbf = fl[0]>0.5f;
  int idx = blockIdx.x*256 + threadIdx.x;
  if (idx >= 128*PAD) return;
  int n = idx/PAD, k = idx%PAD;
  float v = 0.f;
  if (k < 128) v = (n<64) ? ldf(aw1, (size_t)k*64 + n, isbf)
                          : ldf(aw1, (size_t)(128+k)*64 + (n-64), isbf);
  dst[idx] = f2b(v);
  if (idx < 128) bcat[idx] = f2b(idx<64 ? ldf(ab1, idx, isbf) : 0.f);
}

// ---- MFMA GEMM v2: A direct from global (no sA LDS), W-only LDS ----
// 64 rows/block, 4 waves x 16 rows; 16x16x32 bf16; ntiles=Nout/16; ksteps=K/32.
__global__ __launch_bounds__(256) void k_mgemm(
    const void* __restrict__ Aext, const bf16* __restrict__ Ab,
    const float* __restrict__ Af, int K,
    const bf16* __restrict__ Wt, const void* __restrict__ bias, int Boff, int Nout,
    bf16* __restrict__ outB, float* __restrict__ outF, void* __restrict__ outE,
    const void* __restrict__ ts, int act, int bbf, const float* __restrict__ fl){
  __shared__ bf16 sW[128*PAD];
  int flA = fl[0] > 0.5f;
  int tid = threadIdx.x;
  int rowBase = blockIdx.x*64;
  {
    int tot = (Nout*PAD)/8;
    const uint4* src = (const uint4*)Wt;
    uint4* dst = (uint4*)sW;
    for (int i = tid; i < tot; i += 256) dst[i] = src[i];
  }
  __syncthreads();
  int wave = tid>>6, lane = tid&63;
  int m0 = wave*16;
  int l15 = lane&15, quad = lane>>4;
  int rowA = rowBase + m0 + l15;           // this lane's A row
  int ntiles = Nout>>4, ksteps = K>>5;
  f32x4 acc[8];
  #pragma unroll
  for (int t=0;t<8;++t) acc[t] = (f32x4){0.f,0.f,0.f,0.f};
  for (int ks=0; ks<ksteps; ++ks){
    int kb = ks*32 + quad*8;
    s8v af;
    size_t gi = (size_t)rowA*K + kb;
    if (Ab)       af = *(const s8v*)(Ab + gi);
    else if (Af){
      float4 f0 = *(const float4*)(Af + gi);
      float4 f1 = *(const float4*)(Af + gi + 4);
      u32 p0=pack2(f0.x,f0.y), p1=pack2(f0.z,f0.w), p2=pack2(f1.x,f1.y), p3=pack2(f1.z,f1.w);
      uint4 uv = (uint4){p0,p1,p2,p3};
      af = *(const s8v*)&uv;
    } else if (flA) af = *(const s8v*)((const bf16*)Aext + gi);
    else {
      const float* Ax = (const float*)Aext;
      float4 f0 = *(const float4*)(Ax + gi);
      float4 f1 = *(const float4*)(Ax + gi + 4);
      u32 p0=pack2(f0.x,f0.y), p1=pack2(f0.z,f0.w), p2=pack2(f1.x,f1.y), p3=pack2(f1.z,f1.w);
      uint4 uv = (uint4){p0,p1,p2,p3};
      af = *(const s8v*)&uv;
    }
    for (int t=0;t<ntiles;++t){
      s8v bfr = *(const s8v*)&sW[(t*16 + l15)*PAD + kb];
      acc[t] = __builtin_amdgcn_mfma_f32_16x16x32_bf16(af, bfr, acc[t], 0, 0, 0);
    }
  }
  int isbfB = bbf || flA;
  for (int t=0;t<ntiles;++t){
    int colN = t*16 + l15;
    float bv = isbfB ? b2f(((const bf16*)bias)[Boff+colN]) : ((const float*)bias)[Boff+colN];
    float w128 = ts ? b2f(sW[colN*PAD + K]) : 0.f;
    #pragma unroll
    for (int r=0;r<4;++r){
      int rowG = rowBase + m0 + quad*4 + r;
      float v = acc[t][r] + bv;
      if (ts) v += (flA ? b2f(((const bf16*)ts)[rowG]) : ((const float*)ts)[rowG]) * w128;
      if (act) v = fmaxf(v, 0.f);
      size_t oi = (size_t)rowG*Nout + colN;
      if (outB) outB[oi] = f2b(v);
      else if (outF) outF[oi] = v;
      else if (flA) ((bf16*)outE)[oi] = f2b(v);
      else ((float*)outE)[oi] = v;
    }
  }
}

// ---- CSR gather: lane owns a feature-pair (u32), scalar row bases ----
// wave = 2 nodes; 16 coalesced dword gathers in flight; zero shuffles.
// modes: 0 spatial, 1 temporal, 2 attn, 3 diffusion, 4 hier-mid, 5 hier-final
// flags: 1 first-heat, 2 finalize(mode3), 4 accum->acc2, 8 accum-first
__global__ __launch_bounds__(256) void g_aggv(
    const bf16* __restrict__ Hin, bf16* __restrict__ out, bf16* __restrict__ hout,
    bf16* __restrict__ acc2,
    const int* __restrict__ colS, const float* __restrict__ wS,
    const float* __restrict__ escS,
    const float* __restrict__ degv, const float* __restrict__ dis,
    const void* __restrict__ heat, int hidx, int mode, int flags, int gidx,
    const float* __restrict__ scal){
  int tid = threadIdx.x;
  int lf = tid & 63;
  int wave = tid >> 6;
  int rr = __builtin_amdgcn_readfirstlane((blockIdx.x*4 + wave)*2);
  const u32* H32 = (const u32*)Hin;
  u32* out32 = (u32*)out;
  u32* ho32 = (u32*)hout;
  u32* ac32 = (u32*)acc2;
  float inv = (mode==2) ? 1.f/fmaxf(scal[7], 1e-30f) : 0.f;
  float tt  = (mode==3) ? ldf(heat, hidx, scal[9]>0.5f) : 0.f;
  float g = scal[10+gidx];
  float w0s=scal[15], w1s=scal[16], w2s=scal[17];

  u32 ld[2][8];
  float wgt[2][8];
  #pragma unroll
  for (int n=0;n<2;++n){
    int rn = rr + n;
    #pragma unroll
    for (int s=0;s<8;++s){
      int c = colS[rn*8+s];                 // scalar (s_load)
      ld[n][s] = (H32 + (size_t)c*64)[lf];  // coalesced dword, scalar base
      float w = 1.f;
      if (mode==0)      w = wS[rn*8+s];
      else if (mode==2) w = escS[rn*8+s]*inv;
      else if (mode==3) w = dis[rn]*dis[c];
      wgt[n][s] = w;
    }
  }
  float aclo[2] = {0.f,0.f}, achi[2] = {0.f,0.f};
  #pragma unroll
  for (int n=0;n<2;++n)
    #pragma unroll
    for (int s=0;s<8;++s){
      aclo[n] += wgt[n][s]*lo2f(ld[n][s]);
      achi[n] += wgt[n][s]*hi2f(ld[n][s]);
    }

  #pragma unroll
  for (int n=0;n<2;++n){
    int rn = rr + n;
    size_t rb = (size_t)rn*64 + lf;
    float vlo, vhi;
    if (mode==0){
      float rd = 1.f/fmaxf(degv[rn], 1.f);
      vlo = fmaxf(aclo[n]*rd, 0.f); vhi = fmaxf(achi[n]*rd, 0.f);
    } else if (mode==1){
      float rd = 1.f/fmaxf(degv[rn], 1.f);
      u32 gv = out32[rb];
      u32 hv = H32[rb];
      float s0 = 1.f/(1.f+expf(-lo2f(gv)));
      float s1 = 1.f/(1.f+expf(-hi2f(gv)));
      vlo = fmaxf(s0*lo2f(hv) + (1.f-s0)*aclo[n]*rd, 0.f);
      vhi = fmaxf(s1*hi2f(hv) + (1.f-s1)*achi[n]*rd, 0.f);
    } else if (mode==2){
      vlo = fmaxf(aclo[n], 0.f); vhi = fmaxf(achi[n], 0.f);
    } else if (mode==3){
      u32 hv = H32[rb];
      float hlo = (1.f-tt)*lo2f(hv) + tt*aclo[n];
      float hhi = (1.f-tt)*hi2f(hv) + tt*achi[n];
      if (!(flags&2)) ho32[rb] = pack2(hlo, hhi);
      if (flags&1){ vlo = hlo; vhi = hhi; }
      else { u32 pv = out32[rb]; vlo = lo2f(pv)+hlo; vhi = hi2f(pv)+hhi; }
      if (flags&2){ vlo = fmaxf(0.2f*vlo, 0.f); vhi = fmaxf(0.2f*vhi, 0.f); }
    } else if (mode==4){
      float rd = 1.f/fmaxf(degv[rn], 1.f);
      vlo = aclo[n]*rd; vhi = achi[n]*rd;
    } else { // 5: h1 in hout, h2 = Hin row, h3 = acc/d
      float rd = 1.f/fmaxf(degv[rn], 1.f);
      u32 a1 = ho32[rb];
      u32 a2 = H32[rb];
      vlo = fmaxf(w0s*lo2f(a1) + w1s*lo2f(a2) + w2s*aclo[n]*rd, 0.f);
      vhi = fmaxf(w0s*hi2f(a1) + w1s*hi2f(a2) + w2s*achi[n]*rd, 0.f);
    }
    out32[rb] = pack2(vlo, vhi);
    if (flags&4){
      float alo = g*vlo, ahi = g*vhi;
      if (!(flags&8)){ u32 bv = ac32[rb]; alo += lo2f(bv); ahi += hi2f(bv); }
      ac32[rb] = pack2(alo, ahi);
    }
  }
}

// ---- edge scores: wave per node (8 edges), 8 lanes/edge ----
__global__ __launch_bounds__(256) void k_edge_score4(
    const float* __restrict__ Huv, const int* __restrict__ colS,
    const void* __restrict__ aw2, const void* __restrict__ ab2,
    float* __restrict__ escS, const float* __restrict__ fl){
  int isbf = fl[0] > 0.5f;
  int tid = threadIdx.x;
  int r = blockIdx.x*4 + (tid>>6);
  int lane = tid & 63;
  int ef = lane>>3, ff = lane&7;
  int p = r*8 + ef;
  int c = colS[p];
  const float* up = Huv + (size_t)r*128 + ff*8;
  const float* vp = Huv + (size_t)c*128 + 64 + ff*8;
  float4 u0 = *(const float4*)up,     u1 = *(const float4*)(up+4);
  float4 v0 = *(const float4*)vp,     v1 = *(const float4*)(vp+4);
  float w2v[8];
  if (isbf){
    const bf16* a2 = (const bf16*)aw2 + ff*8;
    uint4 t4 = *(const uint4*)a2;
    u32 tw[4]={t4.x,t4.y,t4.z,t4.w};
    #pragma unroll
    for (int q=0;q<4;++q){ w2v[2*q]=lo2f(tw[q]); w2v[2*q+1]=hi2f(tw[q]); }
  } else {
    const float* a2 = (const float*)aw2 + ff*8;
    float4 f0 = *(const float4*)a2, f1 = *(const float4*)(a2+4);
    w2v[0]=f0.x; w2v[1]=f0.y; w2v[2]=f0.z; w2v[3]=f0.w;
    w2v[4]=f1.x; w2v[5]=f1.y; w2v[6]=f1.z; w2v[7]=f1.w;
  }
  float s = 0.f;
  s += fmaxf(u0.x+v0.x,0.f)*w2v[0];
  s += fmaxf(u0.y+v0.y,0.f)*w2v[1];
  s += fmaxf(u0.z+v0.z,0.f)*w2v[2];
  s += fmaxf(u0.w+v0.w,0.f)*w2v[3];
  s += fmaxf(u1.x+v1.x,0.f)*w2v[4];
  s += fmaxf(u1.y+v1.y,0.f)*w2v[5];
  s += fmaxf(u1.z+v1.z,0.f)*w2v[6];
  s += fmaxf(u1.w+v1.w,0.f)*w2v[7];
  s += __shfl_xor(s, 1, 64);
  s += __shfl_xor(s, 2, 64);
  s += __shfl_xor(s, 4, 64);
  if (ff == 0) escS[p] = s + ldf(ab2, 0, isbf);
}

// global softmax over E scores
__global__ void k_score_max(const float4* __restrict__ sc4, float* scal){
  __shared__ float red[4];
  float m = -1e30f;
  for (int i = blockIdx.x*256 + threadIdx.x; i < EE/4; i += 256*256){
    float4 v = sc4[i];
    m = fmaxf(fmaxf(m, fmaxf(v.x,v.y)), fmaxf(v.z,v.w));
  }
  for (int o=32;o;o>>=1) m = fmaxf(m, __shfl_down(m, o, 64));
  if ((threadIdx.x&63)==0) red[threadIdx.x>>6] = m;
  __syncthreads();
  if (threadIdx.x==0){
    m = fmaxf(fmaxf(red[0],red[1]), fmaxf(red[2],red[3]));
    atomicMax((unsigned*)scal + 6, fenc(m));
  }
}
__global__ void k_score_exp(float4* __restrict__ sc4, float* scal){
  __shared__ float red[4];
  float mx = fdec(((const unsigned*)scal)[6]);
  float s = 0.f;
  for (int i = blockIdx.x*256 + threadIdx.x; i < EE/4; i += 256*256){
    float4 v = sc4[i];
    v.x = expf(v.x-mx); v.y = expf(v.y-mx); v.z = expf(v.z-mx); v.w = expf(v.w-mx);
    sc4[i] = v;
    s += v.x+v.y+v.z+v.w;
  }
  for (int o=32;o;o>>=1) s += __shfl_down(s, o, 64);
  if ((threadIdx.x&63)==0) red[threadIdx.x>>6] = s;
  __syncthreads();
  if (threadIdx.x==0) atomicAdd(&scal[7], red[0]+red[1]+red[2]+red[3]);
}

extern "C" void kernel_launch(void* const* d_in, const int* in_sizes, int n_in,
                              void* d_out, int out_size, void* d_ws, size_t ws_size,
                              hipStream_t stream){
  (void)in_sizes; (void)n_in;
  const void* x    = d_in[0];
  const int*  ei   = (const int*)d_in[1];
  const void* tsv  = d_in[2];
  const void* ew   = d_in[3];
  const void* prev = d_in[4];
  const void* gum  = d_in[5];
  const void* cw1  = d_in[6];
  const void* cb1  = d_in[7];
  const void* cw2  = d_in[8];
  const void* cb2  = d_in[9];
  const void* mbias= d_in[10];
  const void* aw1  = d_in[11];
  const void* ab1  = d_in[12];
  const void* aw2  = d_in[13];
  const void* ab2  = d_in[14];
  const void* heat = d_in[15];
  const void* tgw  = d_in[16];
  const void* tgb  = d_in[17];
  const void* scw  = d_in[18];
  const void* spw  = d_in[19];
  const void* spb  = d_in[20];
  const void* tww  = d_in[21];
  const void* twb  = d_in[22];
  const void* atw  = d_in[23];
  const void* atb  = d_in[24];
  const void* diw  = d_in[25];
  const void* dib  = d_in[26];
  const void* hiw  = d_in[27];
  const void* hib  = d_in[28];
  const void* ow1  = d_in[29];
  const void* ob1  = d_in[30];
  const void* ow2  = d_in[31];
  const void* ob2  = d_in[32];
  const int* row = ei, *col = ei + EE;

  const size_t WT10 = 10*128*PAD, WTE = 128*PAD, WTO = 64*PAD;
  size_t need = (size_t)NF*2*4 + (size_t)EE*4*3 + (size_t)NN*4*4
              + (WT10 + WTE*2 + WTO*2 + 128)*2 + 256;
  if (ws_size < need){
    k_sentinel<<<(out_size+255)/256,256,0,stream>>>((u16*)d_out, out_size);
    return;
  }
  bf16* Hb   = (bf16*)d_ws;
  bf16* Hb2  = Hb + (size_t)NF;
  bf16* B1   = Hb2 + (size_t)NF;
  bf16* B2   = B1 + (size_t)NF;
  float* escS= (float*)(B2 + (size_t)NF);
  int*   colS= (int*)(escS + EE);
  float* wS  = (float*)(colS + EE);
  int*   cnt = (int*)(wS + EE);
  float* deg = (float*)(cnt + NN);
  float* degw= deg + NN;
  float* dis = degw + NN;
  bf16* wt_l = (bf16*)(dis + NN);      // 10 layers: sp0,sp1,tw0,tw1,at0,at1,di0,di1,hi0,hi1
  bf16* wt_tg= wt_l + WT10;
  bf16* wt_ct= wt_tg + WTE;
  bf16* wt_o1= wt_ct + WTE;
  bf16* wt_o2= wt_o1 + WTO;
  bf16* bcat = wt_o2 + WTO;
  float* scal= (float*)(bcat + 128);
  const float* fl = scal + 9;
  float* Huv = (float*)Hb2;            // fp32 N*128 overlay (Hb2+B1) during attention

  const int TB = 256;
  const int GAG = NN/8;                // g_aggv: 4 waves x 2 nodes per block
  const int GMM = NN/64;

  // ---- prologue ----
  k_init<<<1,64,0,stream>>>(scal);
  k_probe<<<EE/8/TB,TB,0,stream>>>((const uint4*)ew, scal);
  k_flag<<<1,64,0,stream>>>(scal);
  k_wt10<<<(10*128*PAD+TB-1)/TB,TB,0,stream>>>(spw, tww, atw, diw, hiw, wt_l, fl);
  k_wt<<<(128*PAD+TB-1)/TB,TB,0,stream>>>(tgw, 129, 128, wt_tg, fl);
  k_wt<<<(64*PAD+TB-1)/TB,TB,0,stream>>>(ow1, 128, 64, wt_o1, fl);
  k_wt<<<(64*PAD+TB-1)/TB,TB,0,stream>>>(ow2, 64, 64, wt_o2, fl);
  k_wt_cat<<<(128*PAD+TB-1)/TB,TB,0,stream>>>(aw1, ab1, wt_ct, bcat, fl);
  k_fill<<<NN/TB,TB,0,stream>>>((float*)cnt, 0.f, NN);
  k_csr<<<EE/TB,TB,0,stream>>>(row, col, ew, cnt, colS, wS, scal);
  k_node<<<NN/TB,TB,0,stream>>>(cnt, wS, deg, degw, dis, scal);
  k_x_stats<<<512,TB,0,stream>>>(x, scal);
  k_ctrl<<<1,128,0,stream>>>(scal, prev, cw1, cb1, cw2, cb2, mbias, gum, scw);

  auto mgemm = [&](const void* Aext, const bf16* Ab, const float* Af, int K,
                   const bf16* Wt, const void* B, int Boff, int Nout,
                   bf16* oB, float* oF, void* oE, const void* tsp, int act, int bbf){
    k_mgemm<<<GMM, TB, 0, stream>>>(Aext, Ab, Af, K, Wt, B, Boff, Nout,
                                    oB, oF, oE, tsp, act, bbf, fl);
  };
  auto agg = [&](const bf16* Hin, bf16* out, bf16* ho, int mode, int flags,
                 int gidx, const float* dv, int hidx){
    g_aggv<<<GAG, TB, 0, stream>>>(Hin, out, ho, B2, colS, wS, escS, dv, dis,
                                   heat, hidx, mode, flags, gidx, scal);
  };

  // ---- spatial (g0): state B1 ----
  for (int i=0;i<2;++i){
    mgemm(i?nullptr:x, i?B1:nullptr, nullptr, 128, wt_l + (size_t)i*WTE, spb, i*128, 128,
          Hb, nullptr, nullptr, nullptr, 0, 0);
    agg(Hb, B1, nullptr, 0, i?(4|8):0, 0, degw, 0);
  }

  // ---- temporal (g1) ----
  for (int i=0;i<2;++i){
    mgemm(i?nullptr:x, i?B1:nullptr, nullptr, 128, wt_l + (size_t)(2+i)*WTE, twb, i*128, 128,
          Hb, nullptr, nullptr, nullptr, 0, 0);
    mgemm(nullptr, Hb, nullptr, 128, wt_tg, tgb, 0, 128,
          B1, nullptr, nullptr, tsv, 0, 0);                 // gate preact -> B1
    agg(Hb, B1, nullptr, 1, i?4:0, 1, deg, 0);
  }

  // ---- attention (g2) ----
  for (int i=0;i<2;++i){
    mgemm(i?nullptr:x, i?B1:nullptr, nullptr, 128, wt_l + (size_t)(4+i)*WTE, atb, i*128, 128,
          Hb, nullptr, nullptr, nullptr, 0, 0);
    mgemm(nullptr, Hb, nullptr, 128, wt_ct, bcat, 0, 128,
          nullptr, Huv, nullptr, nullptr, 0, 1);            // Huv fp32
    k_edge_score4<<<NN/4,TB,0,stream>>>(Huv, colS, aw2, ab2, escS, fl);
    k_init_attn<<<1,64,0,stream>>>(scal);
    k_score_max<<<256,TB,0,stream>>>((const float4*)escS, scal);
    k_score_exp<<<256,TB,0,stream>>>((float4*)escS, scal);
    agg(Hb, B1, nullptr, 2, i?4:0, 2, deg, 0);
  }

  // ---- diffusion (g3) ----
  for (int i=0;i<2;++i){
    mgemm(i?nullptr:x, i?B1:nullptr, nullptr, 128, wt_l + (size_t)(6+i)*WTE, dib, i*128, 128,
          Hb, nullptr, nullptr, nullptr, 0, 0);
    bf16* hin = Hb; bf16* hot = Hb2;
    for (int j=0;j<5;++j){
      int flags = (j==0?1:0) | (j==4?2:0) | ((i==1&&j==4)?4:0);
      agg(hin, B1, hot, 3, flags, 3, deg, j);
      bf16* t = hin; hin = hot; hot = t;
    }
  }

  // ---- hierarchical (g4) ----
  for (int i=0;i<2;++i){
    mgemm(i?nullptr:x, i?B1:nullptr, nullptr, 128, wt_l + (size_t)(8+i)*WTE, hib, i*128, 128,
          Hb, nullptr, nullptr, nullptr, 0, 0);
    agg(Hb,  Hb2, nullptr, 4, 0, 4, deg, 0);                // h1 -> Hb2
    agg(Hb2, Hb,  nullptr, 4, 0, 4, deg, 0);                // h2 -> Hb
    agg(Hb,  B1,  Hb2,     5, i?4:0, 4, deg, 0);            // h3+combine -> B1
  }

  // ---- output MLP ----
  mgemm(nullptr, B2, nullptr, 128, wt_o1, ob1, 0, 64,
        nullptr, (float*)Hb, nullptr, nullptr, 1, 0);
  mgemm(nullptr, nullptr, (float*)Hb, 64, wt_o2, ob2, 0, 64,
        nullptr, nullptr, d_out, nullptr, 0, 0);
}

// Round 9
// 1411.025 us; speedup vs baseline: 1.0756x; 1.0049x over previous
//
#include <hip/hip_runtime.h>
#include <hip/hip_bf16.h>
#include <math.h>

// MorphingGNN MI355X — round 8: attention Huv factorization stored as split
// bf16 U|V (N x 64 each) — halves the edge-score random-gather volume
// (134 -> 67 MB) and the Huv write. Gather g_aggv at measured random-256B
// fabric ceiling ~2.2 TB/s (3 independent implementations agree) — unchanged.

#define NN   65536
#define EE   524288
#define HH   128
#define NF   (NN*HH)
#define PAD  136          // Wt row stride in bf16 elems

typedef __hip_bfloat16 bf16;
typedef unsigned int   u32;
typedef unsigned short u16;
typedef __attribute__((ext_vector_type(8))) short s8v;
typedef __attribute__((ext_vector_type(4))) float f32x4;

__device__ __forceinline__ float b2f(bf16 v){ return __bfloat162float(v); }
__device__ __forceinline__ bf16  f2b(float v){ return __float2bfloat16(v); }
__device__ __forceinline__ float lo2f(u32 u){ return __uint_as_float(u<<16); }
__device__ __forceinline__ float hi2f(u32 u){ return __uint_as_float(u & 0xffff0000u); }
__device__ __forceinline__ u32 pack2(float a, float b){
  bf16 ba = f2b(a), bb = f2b(b);
  u16 ua = *reinterpret_cast<u16*>(&ba);
  u16 ub = *reinterpret_cast<u16*>(&bb);
  return ((u32)ub<<16) | (u32)ua;
}
__device__ __forceinline__ unsigned fenc(float f){ unsigned u=__float_as_uint(f); return (u&0x80000000u)?~u:(u|0x80000000u); }
__device__ __forceinline__ float fdec(unsigned u){ return __uint_as_float((u&0x80000000u)?(u&0x7fffffffu):~u); }
__device__ __forceinline__ float ldf(const void* p, size_t i, int isbf){
  return isbf ? b2f(((const bf16*)p)[i]) : ((const float*)p)[i];
}

// scal: 0 sumx,1 sumx2,2 sumd,3 sumd2,4 zc,5 sumew,6 attnmax-enc,7 attnsumexp,
//       8 probemax-enc,9 dtype flag,10..14 g,15..17 wsc

__global__ void k_fill(float* p, float v, int n){
  int i = blockIdx.x*blockDim.x + threadIdx.x;
  if (i < n) p[i] = v;
}
__global__ void k_sentinel(u16* p, int n){
  int i = blockIdx.x*blockDim.x + threadIdx.x;
  if (i < n) p[i] = 0x4640;
}
__global__ void k_init(float* scal){
  int i = threadIdx.x;
  if (i < 32) scal[i] = 0.f;
  if (i == 6) ((unsigned*)scal)[6] = 0x007fffffu;
  if (i == 8) ((unsigned*)scal)[8] = 0x80000000u;
}
__global__ void k_init_attn(float* scal){
  if (threadIdx.x==0){ ((unsigned*)scal)[6] = 0x007fffffu; scal[7] = 0.f; }
}

// dtype probe over edge_weight interpreted as bf16
__global__ void k_probe(const uint4* __restrict__ ew4, float* scal){
  __shared__ float red[4];
  int i = blockIdx.x*256 + threadIdx.x;
  uint4 v = ew4[i];
  float m = 0.f;
  u32 ws[4] = {v.x, v.y, v.z, v.w};
  #pragma unroll
  for (int q=0;q<4;++q){
    float a = lo2f(ws[q]), b = hi2f(ws[q]);
    a = isfinite(a) ? fabsf(a) : 1e30f;
    b = isfinite(b) ? fabsf(b) : 1e30f;
    m = fmaxf(m, fmaxf(a,b));
  }
  for (int o=32;o;o>>=1) m = fmaxf(m, __shfl_down(m, o, 64));
  if ((threadIdx.x&63)==0) red[threadIdx.x>>6] = m;
  __syncthreads();
  if (threadIdx.x==0){
    m = fmaxf(fmaxf(red[0],red[1]), fmaxf(red[2],red[3]));
    atomicMax((unsigned*)scal + 8, fenc(m));
  }
}
__global__ void k_flag(float* scal){
  if (threadIdx.x==0){
    float m = fdec(((const unsigned*)scal)[8]);
    scal[9] = (m < 64.f) ? 1.f : 0.f;
  }
}

// CSR build: p=r*8+slot
__global__ void k_csr(const int* __restrict__ row, const int* __restrict__ col,
                      const void* __restrict__ ew, int* cnt,
                      int* __restrict__ colS, float* __restrict__ wS, const float* scal){
  int isbf = scal[9] > 0.5f;
  int e = blockIdx.x*blockDim.x + threadIdx.x;
  int r = row[e];
  float w = ldf(ew, e, isbf);
  int slot = atomicAdd(&cnt[r], 1) & 7;
  int p = r*8 + slot;
  colS[p] = col[e];
  wS[p] = w;
}

// per-node arrays + block-reduced stats
__global__ void k_node(const int* __restrict__ cnt, const float* __restrict__ wS,
                       float* deg, float* degw, float* dis, float* scal){
  __shared__ float red[4][4];
  int i = blockIdx.x*256 + threadIdx.x;
  float dd = (float)cnt[i];
  const float4* w4 = (const float4*)(wS + i*8);
  float4 wa = w4[0], wb = w4[1];
  float s = wa.x+wa.y+wa.z+wa.w + wb.x+wb.y+wb.z+wb.w;
  deg[i] = dd; degw[i] = s;
  dis[i] = (dd>0.f) ? (1.f/sqrtf(dd)) : 1e8f;
  float d = dd, d2 = dd*dd, z = (dd==0.f)?1.f:0.f, sw = s;
  for (int o=32;o;o>>=1){
    d += __shfl_down(d,o,64); d2 += __shfl_down(d2,o,64);
    z += __shfl_down(z,o,64); sw += __shfl_down(sw,o,64);
  }
  int wv = threadIdx.x>>6;
  if ((threadIdx.x&63)==0){ red[wv][0]=d; red[wv][1]=d2; red[wv][2]=z; red[wv][3]=sw; }
  __syncthreads();
  if (threadIdx.x==0){
    float a0=0,a1=0,a2=0,a3=0;
    for (int w=0;w<4;++w){ a0+=red[w][0]; a1+=red[w][1]; a2+=red[w][2]; a3+=red[w][3]; }
    atomicAdd(&scal[2],a0); atomicAdd(&scal[3],a1);
    atomicAdd(&scal[4],a2); atomicAdd(&scal[5],a3);
  }
}

// x stats: 512 blocks, vectorized, 2 atomics/block
__global__ void k_x_stats(const void* __restrict__ x, float* scal){
  __shared__ float red[4][2];
  int isbf = scal[9] > 0.5f;
  float s=0.f, s2=0.f;
  int gtid = blockIdx.x*256 + threadIdx.x;
  if (isbf){
    const uint4* p = (const uint4*)x;
    for (int i = gtid; i < NF/8; i += 512*256){
      uint4 v = p[i];
      u32 ws[4] = {v.x,v.y,v.z,v.w};
      #pragma unroll
      for (int q=0;q<4;++q){
        float a=lo2f(ws[q]), b=hi2f(ws[q]);
        s += a+b; s2 += a*a + b*b;
      }
    }
  } else {
    const float4* p = (const float4*)x;
    for (int i = gtid; i < NF/4; i += 512*256){
      float4 v = p[i];
      s += v.x+v.y+v.z+v.w;
      s2 += v.x*v.x + v.y*v.y + v.z*v.z + v.w*v.w;
    }
  }
  for (int o=32;o;o>>=1){ s += __shfl_down(s,o,64); s2 += __shfl_down(s2,o,64); }
  int wv = threadIdx.x>>6;
  if ((threadIdx.x&63)==0){ red[wv][0]=s; red[wv][1]=s2; }
  __syncthreads();
  if (threadIdx.x==0){
    float a0=0,a1=0;
    for (int w=0;w<4;++w){ a0+=red[w][0]; a1+=red[w][1]; }
    atomicAdd(&scal[0],a0); atomicAdd(&scal[1],a1);
  }
}

__global__ void k_ctrl(float* __restrict__ scal, const void* __restrict__ prev,
                       const void* __restrict__ w1, const void* __restrict__ b1,
                       const void* __restrict__ w2, const void* __restrict__ b2,
                       const void* __restrict__ mbias, const void* __restrict__ gum,
                       const void* __restrict__ scw){
  __shared__ float in[136];
  __shared__ float hid[128];
  __shared__ float logits[5];
  int isbf = scal[9] > 0.5f;
  int t = threadIdx.x;
  if (t == 0){
    float sumx=scal[0], sumx2=scal[1], sumd=scal[2], sumd2=scal[3], zc=scal[4], sumew=scal[5];
    float Mf = (float)NF;
    in[0] = (float)NN/1000.f;
    in[1] = (float)EE/(float)NN;
    float vard = (sumd2 - sumd*sumd/(float)NN) / ((float)NN - 1.f);
    in[2] = sqrtf(fmaxf(vard, 0.f));
    in[3] = zc / (float)NN;
    in[4] = sumx / Mf;
    float varx = (sumx2 - sumx*sumx/Mf) / (Mf - 1.f);
    in[5] = sqrtf(fmaxf(varx, 0.f));
    in[6] = sumew / (float)EE;
    in[7] = (float)EE / ((float)NN*(float)NN);
  }
  in[8+t] = ldf(prev, t, isbf);
  __syncthreads();
  float a = ldf(b1, t, isbf);
  for (int i=0;i<136;++i) a += in[i]*ldf(w1, (size_t)i*128+t, isbf);
  hid[t] = fmaxf(a, 0.f);
  __syncthreads();
  if (t < 5){
    float l = ldf(b2, t, isbf);
    for (int j=0;j<128;++j) l += hid[j]*ldf(w2, (size_t)j*5+t, isbf);
    l += ldf(mbias, t, isbf);
    logits[t] = (l + ldf(gum, t, isbf)) * 2.0f;   // /TAU, TAU=0.5
  }
  __syncthreads();
  if (t == 0){
    float m=-1e30f; for (int i=0;i<5;++i) m=fmaxf(m,logits[i]);
    float p[5], s=0.f;
    for (int i=0;i<5;++i){ p[i]=expf(logits[i]-m); s+=p[i]; }
    for (int i=0;i<5;++i){ float pr=p[i]/s; scal[10+i] = (pr>0.001f)?pr:0.f; }
    float sw[3]; float mw=-1e30f;
    for (int i=0;i<3;++i){ sw[i]=ldf(scw,i,isbf); mw=fmaxf(mw,sw[i]); }
    float ss=0.f; for (int i=0;i<3;++i){ sw[i]=expf(sw[i]-mw); ss+=sw[i]; }
    for (int i=0;i<3;++i) scal[15+i]=sw[i]/ss;
  }
}

// ---- weight transposes: W[k][n] -> Wt[n*PAD + k] bf16 ----
__global__ void k_wt10(const void* w0,const void* w1,const void* w2,const void* w3,const void* w4,
                       bf16* dst, const float* fl){
  int isbf = fl[0]>0.5f;
  int idx = blockIdx.x*256 + threadIdx.x;
  if (idx >= 10*128*PAD) return;
  int wsel = idx/(128*PAD), within = idx%(128*PAD);
  int n = within/PAD, k = within%PAD;
  const void* w = wsel<2?w0: wsel<4?w1: wsel<6?w2: wsel<8?w3: w4;
  size_t lay = (size_t)(wsel&1)*16384;
  float v = (k<128) ? ldf(w, lay + (size_t)k*128 + n, isbf) : 0.f;
  dst[idx] = f2b(v);
}
__global__ void k_wt(const void* W, int K, int Nout, bf16* dst, const float* fl){
  int isbf = fl[0]>0.5f;
  int idx = blockIdx.x*256 + threadIdx.x;
  if (idx >= Nout*PAD) return;
  int n = idx/PAD, k = idx%PAD;
  float v = (k<K) ? ldf(W, (size_t)k*Nout + n, isbf) : 0.f;
  dst[idx] = f2b(v);
}
__global__ void k_wt_cat(const void* aw1, const void* ab1, bf16* dst, bf16* bcat,
                         const float* fl){
  int isbf = fl[0]>0.5f;
  int idx = blockIdx.x*256 + threadIdx.x;
  if (idx >= 128*PAD) return;
  int n = idx/PAD, k = idx%PAD;
  float v = 0.f;
  if (k < 128) v = (n<64) ? ldf(aw1, (size_t)k*64 + n, isbf)
                          : ldf(aw1, (size_t)(128+k)*64 + (n-64), isbf);
  dst[idx] = f2b(v);
  if (idx < 128) bcat[idx] = f2b(idx<64 ? ldf(ab1, idx, isbf) : 0.f);
}

// ---- MFMA GEMM: A direct from global, W-only LDS; optional split-U|V out ----
__global__ __launch_bounds__(256) void k_mgemm(
    const void* __restrict__ Aext, const bf16* __restrict__ Ab,
    const float* __restrict__ Af, int K,
    const bf16* __restrict__ Wt, const void* __restrict__ bias, int Boff, int Nout,
    bf16* __restrict__ outB, float* __restrict__ outF, void* __restrict__ outE,
    const void* __restrict__ ts, int act, int bbf, int split,
    const float* __restrict__ fl){
  __shared__ bf16 sW[128*PAD];
  int flA = fl[0] > 0.5f;
  int tid = threadIdx.x;
  int rowBase = blockIdx.x*64;
  {
    int tot = (Nout*PAD)/8;
    const uint4* src = (const uint4*)Wt;
    uint4* dst = (uint4*)sW;
    for (int i = tid; i < tot; i += 256) dst[i] = src[i];
  }
  __syncthreads();
  int wave = tid>>6, lane = tid&63;
  int m0 = wave*16;
  int l15 = lane&15, quad = lane>>4;
  int rowA = rowBase + m0 + l15;
  int ntiles = Nout>>4, ksteps = K>>5;
  f32x4 acc[8];
  #pragma unroll
  for (int t=0;t<8;++t) acc[t] = (f32x4){0.f,0.f,0.f,0.f};
  for (int ks=0; ks<ksteps; ++ks){
    int kb = ks*32 + quad*8;
    s8v af;
    size_t gi = (size_t)rowA*K + kb;
    if (Ab)       af = *(const s8v*)(Ab + gi);
    else if (Af){
      float4 f0 = *(const float4*)(Af + gi);
      float4 f1 = *(const float4*)(Af + gi + 4);
      u32 p0=pack2(f0.x,f0.y), p1=pack2(f0.z,f0.w), p2=pack2(f1.x,f1.y), p3=pack2(f1.z,f1.w);
      uint4 uv = (uint4){p0,p1,p2,p3};
      af = *(const s8v*)&uv;
    } else if (flA) af = *(const s8v*)((const bf16*)Aext + gi);
    else {
      const float* Ax = (const float*)Aext;
      float4 f0 = *(const float4*)(Ax + gi);
      float4 f1 = *(const float4*)(Ax + gi + 4);
      u32 p0=pack2(f0.x,f0.y), p1=pack2(f0.z,f0.w), p2=pack2(f1.x,f1.y), p3=pack2(f1.z,f1.w);
      uint4 uv = (uint4){p0,p1,p2,p3};
      af = *(const s8v*)&uv;
    }
    for (int t=0;t<ntiles;++t){
      s8v bfr = *(const s8v*)&sW[(t*16 + l15)*PAD + kb];
      acc[t] = __builtin_amdgcn_mfma_f32_16x16x32_bf16(af, bfr, acc[t], 0, 0, 0);
    }
  }
  int isbfB = bbf || flA;
  for (int t=0;t<ntiles;++t){
    int colN = t*16 + l15;
    float bv = isbfB ? b2f(((const bf16*)bias)[Boff+colN]) : ((const float*)bias)[Boff+colN];
    float w128 = ts ? b2f(sW[colN*PAD + K]) : 0.f;
    #pragma unroll
    for (int r=0;r<4;++r){
      int rowG = rowBase + m0 + quad*4 + r;
      float v = acc[t][r] + bv;
      if (ts) v += (flA ? b2f(((const bf16*)ts)[rowG]) : ((const float*)ts)[rowG]) * w128;
      if (act) v = fmaxf(v, 0.f);
      if (split){
        bf16* Ub = (bf16*)outE;
        bf16* Vb = Ub + (size_t)NN*64;
        size_t oi = (size_t)rowG*64 + (colN & 63);
        (colN < 64 ? Ub : Vb)[oi] = f2b(v);
      } else {
        size_t oi = (size_t)rowG*Nout + colN;
        if (outB) outB[oi] = f2b(v);
        else if (outF) outF[oi] = v;
        else if (flA) ((bf16*)outE)[oi] = f2b(v);
        else ((float*)outE)[oi] = v;
      }
    }
  }
}

// ---- CSR gather: lane owns a feature-pair (u32), scalar row bases ----
// wave = 2 nodes; 16 coalesced dword gathers in flight; zero shuffles.
// modes: 0 spatial, 1 temporal, 2 attn, 3 diffusion, 4 hier-mid, 5 hier-final
// flags: 1 first-heat, 2 finalize(mode3), 4 accum->acc2, 8 accum-first
__global__ __launch_bounds__(256) void g_aggv(
    const bf16* __restrict__ Hin, bf16* __restrict__ out, bf16* __restrict__ hout,
    bf16* __restrict__ acc2,
    const int* __restrict__ colS, const float* __restrict__ wS,
    const float* __restrict__ escS,
    const float* __restrict__ degv, const float* __restrict__ dis,
    const void* __restrict__ heat, int hidx, int mode, int flags, int gidx,
    const float* __restrict__ scal){
  int tid = threadIdx.x;
  int lf = tid & 63;
  int wave = tid >> 6;
  int rr = __builtin_amdgcn_readfirstlane((blockIdx.x*4 + wave)*2);
  const u32* H32 = (const u32*)Hin;
  u32* out32 = (u32*)out;
  u32* ho32 = (u32*)hout;
  u32* ac32 = (u32*)acc2;
  float inv = (mode==2) ? 1.f/fmaxf(scal[7], 1e-30f) : 0.f;
  float tt  = (mode==3) ? ldf(heat, hidx, scal[9]>0.5f) : 0.f;
  float g = scal[10+gidx];
  float w0s=scal[15], w1s=scal[16], w2s=scal[17];

  u32 ld[2][8];
  float wgt[2][8];
  #pragma unroll
  for (int n=0;n<2;++n){
    int rn = rr + n;
    #pragma unroll
    for (int s=0;s<8;++s){
      int c = colS[rn*8+s];                 // scalar (s_load)
      ld[n][s] = (H32 + (size_t)c*64)[lf];  // coalesced dword, scalar base
      float w = 1.f;
      if (mode==0)      w = wS[rn*8+s];
      else if (mode==2) w = escS[rn*8+s]*inv;
      else if (mode==3) w = dis[rn]*dis[c];
      wgt[n][s] = w;
    }
  }
  float aclo[2] = {0.f,0.f}, achi[2] = {0.f,0.f};
  #pragma unroll
  for (int n=0;n<2;++n)
    #pragma unroll
    for (int s=0;s<8;++s){
      aclo[n] += wgt[n][s]*lo2f(ld[n][s]);
      achi[n] += wgt[n][s]*hi2f(ld[n][s]);
    }

  #pragma unroll
  for (int n=0;n<2;++n){
    int rn = rr + n;
    size_t rb = (size_t)rn*64 + lf;
    float vlo, vhi;
    if (mode==0){
      float rd = 1.f/fmaxf(degv[rn], 1.f);
      vlo = fmaxf(aclo[n]*rd, 0.f); vhi = fmaxf(achi[n]*rd, 0.f);
    } else if (mode==1){
      float rd = 1.f/fmaxf(degv[rn], 1.f);
      u32 gv = out32[rb];
      u32 hv = H32[rb];
      float s0 = 1.f/(1.f+expf(-lo2f(gv)));
      float s1 = 1.f/(1.f+expf(-hi2f(gv)));
      vlo = fmaxf(s0*lo2f(hv) + (1.f-s0)*aclo[n]*rd, 0.f);
      vhi = fmaxf(s1*hi2f(hv) + (1.f-s1)*achi[n]*rd, 0.f);
    } else if (mode==2){
      vlo = fmaxf(aclo[n], 0.f); vhi = fmaxf(achi[n], 0.f);
    } else if (mode==3){
      u32 hv = H32[rb];
      float hlo = (1.f-tt)*lo2f(hv) + tt*aclo[n];
      float hhi = (1.f-tt)*hi2f(hv) + tt*achi[n];
      if (!(flags&2)) ho32[rb] = pack2(hlo, hhi);
      if (flags&1){ vlo = hlo; vhi = hhi; }
      else { u32 pv = out32[rb]; vlo = lo2f(pv)+hlo; vhi = hi2f(pv)+hhi; }
      if (flags&2){ vlo = fmaxf(0.2f*vlo, 0.f); vhi = fmaxf(0.2f*vhi, 0.f); }
    } else if (mode==4){
      float rd = 1.f/fmaxf(degv[rn], 1.f);
      vlo = aclo[n]*rd; vhi = achi[n]*rd;
    } else { // 5: h1 in hout, h2 = Hin row, h3 = acc/d
      float rd = 1.f/fmaxf(degv[rn], 1.f);
      u32 a1 = ho32[rb];
      u32 a2 = H32[rb];
      vlo = fmaxf(w0s*lo2f(a1) + w1s*lo2f(a2) + w2s*aclo[n]*rd, 0.f);
      vhi = fmaxf(w0s*hi2f(a1) + w1s*hi2f(a2) + w2s*achi[n]*rd, 0.f);
    }
    out32[rb] = pack2(vlo, vhi);
    if (flags&4){
      float alo = g*vlo, ahi = g*vhi;
      if (!(flags&8)){ u32 bv = ac32[rb]; alo += lo2f(bv); ahi += hi2f(bv); }
      ac32[rb] = pack2(alo, ahi);
    }
  }
}

// ---- edge scores from bf16 U|V: wave per node (8 edges), 8 lanes/edge ----
__global__ __launch_bounds__(256) void k_edge_score4(
    const bf16* __restrict__ U, const int* __restrict__ colS,
    const void* __restrict__ aw2, const void* __restrict__ ab2,
    float* __restrict__ escS, const float* __restrict__ fl){
  int isbf = fl[0] > 0.5f;
  const bf16* V = U + (size_t)NN*64;
  int tid = threadIdx.x;
  int r = blockIdx.x*4 + (tid>>6);
  int lane = tid & 63;
  int ef = lane>>3, ff = lane&7;
  int p = r*8 + ef;
  int c = colS[p];
  uint4 uu = *(const uint4*)(U + (size_t)r*64 + ff*8);
  uint4 vv = *(const uint4*)(V + (size_t)c*64 + ff*8);
  u32 uw[4]={uu.x,uu.y,uu.z,uu.w}, vw[4]={vv.x,vv.y,vv.z,vv.w};
  float w2v[8];
  if (isbf){
    const bf16* a2 = (const bf16*)aw2 + ff*8;
    uint4 t4 = *(const uint4*)a2;
    u32 tw[4]={t4.x,t4.y,t4.z,t4.w};
    #pragma unroll
    for (int q=0;q<4;++q){ w2v[2*q]=lo2f(tw[q]); w2v[2*q+1]=hi2f(tw[q]); }
  } else {
    const float* a2 = (const float*)aw2 + ff*8;
    float4 f0 = *(const float4*)a2, f1 = *(const float4*)(a2+4);
    w2v[0]=f0.x; w2v[1]=f0.y; w2v[2]=f0.z; w2v[3]=f0.w;
    w2v[4]=f1.x; w2v[5]=f1.y; w2v[6]=f1.z; w2v[7]=f1.w;
  }
  float s = 0.f;
  #pragma unroll
  for (int q=0;q<4;++q){
    s += fmaxf(lo2f(uw[q])+lo2f(vw[q]),0.f)*w2v[2*q];
    s += fmaxf(hi2f(uw[q])+hi2f(vw[q]),0.f)*w2v[2*q+1];
  }
  s += __shfl_xor(s, 1, 64);
  s += __shfl_xor(s, 2, 64);
  s += __shfl_xor(s, 4, 64);
  if (ff == 0) escS[p] = s + ldf(ab2, 0, isbf);
}

// global softmax over E scores
__global__ void k_score_max(const float4* __restrict__ sc4, float* scal){
  __shared__ float red[4];
  float m = -1e30f;
  for (int i = blockIdx.x*256 + threadIdx.x; i < EE/4; i += 256*256){
    float4 v = sc4[i];
    m = fmaxf(fmaxf(m, fmaxf(v.x,v.y)), fmaxf(v.z,v.w));
  }
  for (int o=32;o;o>>=1) m = fmaxf(m, __shfl_down(m, o, 64));
  if ((threadIdx.x&63)==0) red[threadIdx.x>>6] = m;
  __syncthreads();
  if (threadIdx.x==0){
    m = fmaxf(fmaxf(red[0],red[1]), fmaxf(red[2],red[3]));
    atomicMax((unsigned*)scal + 6, fenc(m));
  }
}
__global__ void k_score_exp(float4* __restrict__ sc4, float* scal){
  __shared__ float red[4];
  float mx = fdec(((const unsigned*)scal)[6]);
  float s = 0.f;
  for (int i = blockIdx.x*256 + threadIdx.x; i < EE/4; i += 256*256){
    float4 v = sc4[i];
    v.x = expf(v.x-mx); v.y = expf(v.y-mx); v.z = expf(v.z-mx); v.w = expf(v.w-mx);
    sc4[i] = v;
    s += v.x+v.y+v.z+v.w;
  }
  for (int o=32;o;o>>=1) s += __shfl_down(s, o, 64);
  if ((threadIdx.x&63)==0) red[threadIdx.x>>6] = s;
  __syncthreads();
  if (threadIdx.x==0) atomicAdd(&scal[7], red[0]+red[1]+red[2]+red[3]);
}

extern "C" void kernel_launch(void* const* d_in, const int* in_sizes, int n_in,
                              void* d_out, int out_size, void* d_ws, size_t ws_size,
                              hipStream_t stream){
  (void)in_sizes; (void)n_in;
  const void* x    = d_in[0];
  const int*  ei   = (const int*)d_in[1];
  const void* tsv  = d_in[2];
  const void* ew   = d_in[3];
  const void* prev = d_in[4];
  const void* gum  = d_in[5];
  const void* cw1  = d_in[6];
  const void* cb1  = d_in[7];
  const void* cw2  = d_in[8];
  const void* cb2  = d_in[9];
  const void* mbias= d_in[10];
  const void* aw1  = d_in[11];
  const void* ab1  = d_in[12];
  const void* aw2  = d_in[13];
  const void* ab2  = d_in[14];
  const void* heat = d_in[15];
  const void* tgw  = d_in[16];
  const void* tgb  = d_in[17];
  const void* scw  = d_in[18];
  const void* spw  = d_in[19];
  const void* spb  = d_in[20];
  const void* tww  = d_in[21];
  const void* twb  = d_in[22];
  const void* atw  = d_in[23];
  const void* atb  = d_in[24];
  const void* diw  = d_in[25];
  const void* dib  = d_in[26];
  const void* hiw  = d_in[27];
  const void* hib  = d_in[28];
  const void* ow1  = d_in[29];
  const void* ob1  = d_in[30];
  const void* ow2  = d_in[31];
  const void* ob2  = d_in[32];
  const int* row = ei, *col = ei + EE;

  const size_t WT10 = 10*128*PAD, WTE = 128*PAD, WTO = 64*PAD;
  size_t need = (size_t)NF*2*4 + (size_t)EE*4*3 + (size_t)NN*4*4
              + (WT10 + WTE*2 + WTO*2 + 128)*2 + 256;
  if (ws_size < need){
    k_sentinel<<<(out_size+255)/256,256,0,stream>>>((u16*)d_out, out_size);
    return;
  }
  bf16* Hb   = (bf16*)d_ws;
  bf16* Hb2  = Hb + (size_t)NF;
  bf16* B1   = Hb2 + (size_t)NF;
  bf16* B2   = B1 + (size_t)NF;
  float* escS= (float*)(B2 + (size_t)NF);
  int*   colS= (int*)(escS + EE);
  float* wS  = (float*)(colS + EE);
  int*   cnt = (int*)(wS + EE);
  float* deg = (float*)(cnt + NN);
  float* degw= deg + NN;
  float* dis = degw + NN;
  bf16* wt_l = (bf16*)(dis + NN);      // 10 layers: sp0,sp1,tw0,tw1,at0,at1,di0,di1,hi0,hi1
  bf16* wt_tg= wt_l + WT10;
  bf16* wt_ct= wt_tg + WTE;
  bf16* wt_o1= wt_ct + WTE;
  bf16* wt_o2= wt_o1 + WTO;
  bf16* bcat = wt_o2 + WTO;
  float* scal= (float*)(bcat + 128);
  const float* fl = scal + 9;
  bf16* UV = Hb2;                      // bf16 U|V (N*64 each) overlay on Hb2 during attention

  const int TB = 256;
  const int GAG = NN/8;                // g_aggv: 4 waves x 2 nodes per block
  const int GMM = NN/64;

  // ---- prologue ----
  k_init<<<1,64,0,stream>>>(scal);
  k_probe<<<EE/8/TB,TB,0,stream>>>((const uint4*)ew, scal);
  k_flag<<<1,64,0,stream>>>(scal);
  k_wt10<<<(10*128*PAD+TB-1)/TB,TB,0,stream>>>(spw, tww, atw, diw, hiw, wt_l, fl);
  k_wt<<<(128*PAD+TB-1)/TB,TB,0,stream>>>(tgw, 129, 128, wt_tg, fl);
  k_wt<<<(64*PAD+TB-1)/TB,TB,0,stream>>>(ow1, 128, 64, wt_o1, fl);
  k_wt<<<(64*PAD+TB-1)/TB,TB,0,stream>>>(ow2, 64, 64, wt_o2, fl);
  k_wt_cat<<<(128*PAD+TB-1)/TB,TB,0,stream>>>(aw1, ab1, wt_ct, bcat, fl);
  k_fill<<<NN/TB,TB,0,stream>>>((float*)cnt, 0.f, NN);
  k_csr<<<EE/TB,TB,0,stream>>>(row, col, ew, cnt, colS, wS, scal);
  k_node<<<NN/TB,TB,0,stream>>>(cnt, wS, deg, degw, dis, scal);
  k_x_stats<<<512,TB,0,stream>>>(x, scal);
  k_ctrl<<<1,128,0,stream>>>(scal, prev, cw1, cb1, cw2, cb2, mbias, gum, scw);

  auto mgemm = [&](const void* Aext, const bf16* Ab, const float* Af, int K,
                   const bf16* Wt, const void* B, int Boff, int Nout,
                   bf16* oB, float* oF, void* oE, const void* tsp, int act, int bbf,
                   int split){
    k_mgemm<<<GMM, TB, 0, stream>>>(Aext, Ab, Af, K, Wt, B, Boff, Nout,
                                    oB, oF, oE, tsp, act, bbf, split, fl);
  };
  auto agg = [&](const bf16* Hin, bf16* out, bf16* ho, int mode, int flags,
                 int gidx, const float* dv, int hidx){
    g_aggv<<<GAG, TB, 0, stream>>>(Hin, out, ho, B2, colS, wS, escS, dv, dis,
                                   heat, hidx, mode, flags, gidx, scal);
  };

  // ---- spatial (g0): state B1 ----
  for (int i=0;i<2;++i){
    mgemm(i?nullptr:x, i?B1:nullptr, nullptr, 128, wt_l + (size_t)i*WTE, spb, i*128, 128,
          Hb, nullptr, nullptr, nullptr, 0, 0, 0);
    agg(Hb, B1, nullptr, 0, i?(4|8):0, 0, degw, 0);
  }

  // ---- temporal (g1) ----
  for (int i=0;i<2;++i){
    mgemm(i?nullptr:x, i?B1:nullptr, nullptr, 128, wt_l + (size_t)(2+i)*WTE, twb, i*128, 128,
          Hb, nullptr, nullptr, nullptr, 0, 0, 0);
    mgemm(nullptr, Hb, nullptr, 128, wt_tg, tgb, 0, 128,
          B1, nullptr, nullptr, tsv, 0, 0, 0);               // gate preact -> B1
    agg(Hb, B1, nullptr, 1, i?4:0, 1, deg, 0);
  }

  // ---- attention (g2) ----
  for (int i=0;i<2;++i){
    mgemm(i?nullptr:x, i?B1:nullptr, nullptr, 128, wt_l + (size_t)(4+i)*WTE, atb, i*128, 128,
          Hb, nullptr, nullptr, nullptr, 0, 0, 0);
    mgemm(nullptr, Hb, nullptr, 128, wt_ct, bcat, 0, 128,
          nullptr, nullptr, UV, nullptr, 0, 1, 1);           // split bf16 U|V
    k_edge_score4<<<NN/4,TB,0,stream>>>(UV, colS, aw2, ab2, escS, fl);
    k_init_attn<<<1,64,0,stream>>>(scal);
    k_score_max<<<256,TB,0,stream>>>((const float4*)escS, scal);
    k_score_exp<<<256,TB,0,stream>>>((float4*)escS, scal);
    agg(Hb, B1, nullptr, 2, i?4:0, 2, deg, 0);
  }

  // ---- diffusion (g3) ----
  for (int i=0;i<2;++i){
    mgemm(i?nullptr:x, i?B1:nullptr, nullptr, 128, wt_l + (size_t)(6+i)*WTE, dib, i*128, 128,
          Hb, nullptr, nullptr, nullptr, 0, 0, 0);
    bf16* hin = Hb; bf16* hot = Hb2;
    for (int j=0;j<5;++j){
      int flags = (j==0?1:0) | (j==4?2:0) | ((i==1&&j==4)?4:0);
      agg(hin, B1, hot, 3, flags, 3, deg, j);
      bf16* t = hin; hin = hot; hot = t;
    }
  }

  // ---- hierarchical (g4) ----
  for (int i=0;i<2;++i){
    mgemm(i?nullptr:x, i?B1:nullptr, nullptr, 128, wt_l + (size_t)(8+i)*WTE, hib, i*128, 128,
          Hb, nullptr, nullptr, nullptr, 0, 0, 0);
    agg(Hb,  Hb2, nullptr, 4, 0, 4, deg, 0);                // h1 -> Hb2
    agg(Hb2, Hb,  nullptr, 4, 0, 4, deg, 0);                // h2 -> Hb
    agg(Hb,  B1,  Hb2,     5, i?4:0, 4, deg, 0);            // h3+combine -> B1
  }

  // ---- output MLP ----
  mgemm(nullptr, B2, nullptr, 128, wt_o1, ob1, 0, 64,
        nullptr, (float*)Hb, nullptr, nullptr, 1, 0, 0);
  mgemm(nullptr, nullptr, (float*)Hb, 64, wt_o2, ob2, 0, 64,
        nullptr, nullptr, d_out, nullptr, 0, 0, 0);
}